// Round 6
// baseline (558.107 us; speedup 1.0000x reference)
//
#include <hip/hip_runtime.h>
#include <hip/hip_fp16.h>
#include <math.h>

// Volume dims (1,1,160,192,160) fp32
#define DD 160
#define HHH 192
#define WWW 160
constexpr int HW = HHH * WWW;          // 30720
constexpr int NV = DD * HHH * WWW;     // 4915200
constexpr int W4 = WWW / 4;            // 40 (tile group granularity)
constexpr int W8 = WWW / 8;            // 20 (whsum/dcc thread granularity)
constexpr int HC = 4;                  // whsum H-chunk
constexpr int DC = 4;                  // dcc D-chunk
constexpr int SC = 8;                  // sobel D-chunk (fallback path only)
constexpr int SCF = 4;                 // fused sobel+lap D-chunk

constexpr int NB_WH  = (W8 * DD * (HHH / HC)) / 256;   // 600
constexpr int NB_SO  = (W4 * HHH * (DD / SC)) / 256;   // 600  (fallback)
constexpr int NB_LAP = (NV / 4) / 256;                 // 4800 (fallback)
constexpr int NB_DCC = (W8 * HHH * (DD / DC)) / 256;   // 600
constexpr int NB_FU  = (W4 * HHH * (DD / SCF)) / 256;  // 1200 (per volume)

// Per-phase XCD-chunked swizzle (proven: halves FETCH via L2 locality).
// Valid bijection when n % 8 == 0 (all phase ranges here are).
__device__ __forceinline__ int xcd_swz(int b, int n) {
    int q = n >> 3;
    return (b & 7) * q + (b >> 3);
}

__device__ __forceinline__ float4 ldg4(const float* __restrict__ p, int idx, bool ok) {
    float4 z = make_float4(0.f, 0.f, 0.f, 0.f);
    return ok ? *(const float4*)(p + idx) : z;
}

__device__ __forceinline__ void st_h4(__half* __restrict__ t, int idx,
                                      float s0, float s1, float s2, float s3) {
    union { __half2 h2[2]; uint2 u; } pk;
    pk.h2[0] = __floats2half2_rn(s0, s1);
    pk.h2[1] = __floats2half2_rn(s2, s3);
    *(uint2*)(t + idx) = pk.u;  // idx%4==0 -> 8B aligned
}

// ---- Interleaved 5-moment tile: group g (4 voxels) = [5][4] fp16 = 40B.
// w8 thread handles two adjacent groups = 80B contiguous = 5x uint4.
__device__ __forceinline__ void st_t5x2(__half* __restrict__ t, int g2, const float S[5][8]) {
    __half tmp[40];
#pragma unroll
    for (int q = 0; q < 5; q++)
#pragma unroll
        for (int k = 0; k < 8; k++)
            tmp[(k >> 2) * 20 + q * 4 + (k & 3)] = __float2half(S[q][k]);
    __half* p = t + (size_t)g2 * 20;
#pragma unroll
    for (int j = 0; j < 5; j++)
        *(uint4*)(p + 8 * j) = *(const uint4*)(tmp + 8 * j);  // g2 even -> 16B aligned
}

__device__ __forceinline__ void ld_t5x2(const __half* __restrict__ t, int g2, float v[5][8]) {
    __half tmp[40];
    const __half* p = t + (size_t)g2 * 20;
#pragma unroll
    for (int j = 0; j < 5; j++)
        *(uint4*)(tmp + 8 * j) = *(const uint4*)(p + 8 * j);
#pragma unroll
    for (int q = 0; q < 5; q++)
#pragma unroll
        for (int k = 0; k < 8; k++)
            v[q][k] = __half2float(tmp[(k >> 2) * 20 + q * 4 + (k & 3)]);
}

// ---- Fused sobel+lap body, ONE volume per thread (4-wide, unchanged) -------
__device__ void fused_body(int t, const float* __restrict__ p,
                           __half* __restrict__ olap, __half* __restrict__ osob) {
    int w = (t % W4) * 4;
    int h = (t / W4) % HHH;
    int c = t / (W4 * HHH);
    int d0 = c * SCF;

    float A1[3][4], A2[3][4], A3[3][4];
    float P6[6], PP4[4], PH[4];
#pragma unroll
    for (int j = 0; j < 3; j++)
#pragma unroll
        for (int k = 0; k < 4; k++) { A1[j][k] = 0.f; A2[j][k] = 0.f; A3[j][k] = 0.f; }
#pragma unroll
    for (int k = 0; k < 6; k++) P6[k] = 0.f;
#pragma unroll
    for (int k = 0; k < 4; k++) { PP4[k] = 0.f; PH[k] = 0.f; }

#pragma unroll
    for (int i = 0; i < SCF + 2; i++) {
        int s = d0 - 1 + i;
#pragma unroll
        for (int k = 0; k < 4; k++) {
            A1[0][k] = A1[1][k]; A2[0][k] = A2[1][k]; A3[0][k] = A3[1][k];
            A1[1][k] = A1[2][k]; A2[1][k] = A2[2][k]; A3[1][k] = A3[2][k];
        }
        float C6[6] = {0.f, 0.f, 0.f, 0.f, 0.f, 0.f};
        float CH[4] = {0.f, 0.f, 0.f, 0.f};
#pragma unroll
        for (int k = 0; k < 4; k++) { A1[2][k] = 0.f; A2[2][k] = 0.f; A3[2][k] = 0.f; }
        if (s >= 0 && s < DD) {
#pragma unroll
            for (int kh = -1; kh <= 1; kh++) {
                int h2 = h + kh;
                if ((unsigned)h2 < (unsigned)HHH) {
                    int rb = (s * HHH + h2) * WWW + w;
                    float4 cen = *(const float4*)(p + rb);
                    float xm = (w > 0) ? p[rb - 1] : 0.f;
                    float xp = (w + 4 < WWW) ? p[rb + 4] : 0.f;
                    float xv[6] = {xm, cen.x, cen.y, cen.z, cen.w, xp};
                    float smh = (kh == 0) ? 2.f : 1.f;
                    float grh = (float)kh;
#pragma unroll
                    for (int k = 0; k < 4; k++) {
                        float gw = xv[k + 2] - xv[k];
                        float pw = xv[k] + xv[k + 1] + xv[k + 2];
                        float sw = pw + xv[k + 1];
                        A1[2][k] += smh * gw;
                        A2[2][k] += sw;
                        A3[2][k] += grh * pw;
                    }
                    if (kh == 0) {
#pragma unroll
                        for (int j = 0; j < 6; j++) C6[j] = xv[j];
                    } else {
#pragma unroll
                        for (int k = 0; k < 4; k++) CH[k] += xv[k + 1];
                    }
                }
            }
        }
        if (i >= 2) {
            int d = s - 1;
            int idx = (d * HHH + h) * WWW + w;
            float vs[4], vl[4];
#pragma unroll
            for (int k = 0; k < 4; k++) {
                float gx = A1[0][k] + A1[1][k] + A1[2][k];
                float gy = A2[2][k] - A2[0][k];
                float gz = A3[0][k] + 2.f * A3[1][k] + A3[2][k];
                vs[k] = sqrtf(gx * gx + gy * gy + gz * gz);
                vl[k] = 6.f * P6[k + 1] - (P6[k] + P6[k + 2] + PH[k] + PP4[k] + C6[k + 1]);
            }
            st_h4(osob, idx, vs[0], vs[1], vs[2], vs[3]);
            st_h4(olap, idx, vl[0], vl[1], vl[2], vl[3]);
        }
#pragma unroll
        for (int k = 0; k < 4; k++) PP4[k] = P6[k + 1];
#pragma unroll
        for (int j = 0; j < 6; j++) P6[j] = C6[j];
#pragma unroll
        for (int k = 0; k < 4; k++) PH[k] = CH[k];
    }
}

// ---- Laplacian body (fallback path only) -----------------------------------
__device__ __forceinline__ void lap_body(int t, const float* __restrict__ a,
                                         const float* __restrict__ b,
                                         __half* __restrict__ oa, __half* __restrict__ ob) {
    int w = (t % W4) * 4;
    int h = (t / W4) % HHH;
    int d = t / (W4 * HHH);
    int idx = (d * HHH + h) * WWW + w;
    bool dok0 = d > 0, dok1 = d < DD - 1, hok0 = h > 0, hok1 = h < HHH - 1;
#pragma unroll
    for (int s = 0; s < 2; s++) {
        const float* p = s ? b : a;
        __half* o = s ? ob : oa;
        float4 c = *(const float4*)(p + idx);
        float m1 = (w > 0) ? p[idx - 1] : 0.f;
        float p4 = (w + 4 < WWW) ? p[idx + 4] : 0.f;
        float4 dm = ldg4(p, idx - HW, dok0);
        float4 dp = ldg4(p, idx + HW, dok1);
        float4 hm = ldg4(p, idx - WWW, hok0);
        float4 hp = ldg4(p, idx + WWW, hok1);
        st_h4(o, idx,
              6.f * c.x - (m1 + c.y + dm.x + dp.x + hm.x + hp.x),
              6.f * c.y - (c.x + c.z + dm.y + dp.y + hm.y + hp.y),
              6.f * c.z - (c.y + c.w + dm.z + dp.z + hm.z + hp.z),
              6.f * c.w - (c.z + p4 + dm.w + dp.w + hm.w + hp.w));
    }
}

// ---- Sobel body (fallback path only) ----------------------------------------
__device__ __forceinline__ void sobel_slice(const float* __restrict__ p, int s, int h, int w,
                                            float a1[4], float a2[4], float a3[4]) {
#pragma unroll
    for (int k = 0; k < 4; k++) { a1[k] = 0.f; a2[k] = 0.f; a3[k] = 0.f; }
#pragma unroll
    for (int kh = -1; kh <= 1; kh++) {
        int h2 = h + kh;
        if ((unsigned)h2 < (unsigned)HHH) {
            int rb = (s * HHH + h2) * WWW + w;
            float4 cen = *(const float4*)(p + rb);
            float xm = (w > 0) ? p[rb - 1] : 0.f;
            float xp = (w + 4 < WWW) ? p[rb + 4] : 0.f;
            float xv[6] = {xm, cen.x, cen.y, cen.z, cen.w, xp};
            float smh = (kh == 0) ? 2.f : 1.f;
            float grh = (float)kh;
#pragma unroll
            for (int k = 0; k < 4; k++) {
                float gw = xv[k + 2] - xv[k];
                float pw = xv[k] + xv[k + 1] + xv[k + 2];
                float sw = pw + xv[k + 1];
                a1[k] += smh * gw;
                a2[k] += sw;
                a3[k] += grh * pw;
            }
        }
    }
}

__device__ __forceinline__ void sobel_body(int t, const float* __restrict__ a,
                                           const float* __restrict__ b,
                                           __half* __restrict__ oa, __half* __restrict__ ob) {
    int w = (t % W4) * 4;
    int h = (t / W4) % HHH;
    int c = t / (W4 * HHH);
    int d0 = c * SC;

    float A1[2][3][4], A2[2][3][4], A3[2][3][4];
#pragma unroll
    for (int r = 0; r < 2; r++)
#pragma unroll
        for (int j = 0; j < 3; j++)
#pragma unroll
            for (int k = 0; k < 4; k++) { A1[r][j][k] = 0.f; A2[r][j][k] = 0.f; A3[r][j][k] = 0.f; }

#pragma unroll
    for (int i = 0; i < SC + 2; i++) {
        int s = d0 - 1 + i;
#pragma unroll
        for (int r = 0; r < 2; r++)
#pragma unroll
            for (int k = 0; k < 4; k++) {
                A1[r][0][k] = A1[r][1][k]; A2[r][0][k] = A2[r][1][k]; A3[r][0][k] = A3[r][1][k];
                A1[r][1][k] = A1[r][2][k]; A2[r][1][k] = A2[r][2][k]; A3[r][1][k] = A3[r][2][k];
            }
        if (s >= 0 && s < DD) {
            sobel_slice(a, s, h, w, A1[0][2], A2[0][2], A3[0][2]);
            sobel_slice(b, s, h, w, A1[1][2], A2[1][2], A3[1][2]);
        } else {
#pragma unroll
            for (int r = 0; r < 2; r++)
#pragma unroll
                for (int k = 0; k < 4; k++) { A1[r][2][k] = 0.f; A2[r][2][k] = 0.f; A3[r][2][k] = 0.f; }
        }
        if (i >= 2) {
            int d = s - 1;
            int idx = (d * HHH + h) * WWW + w;
            float va[4], vb[4];
#pragma unroll
            for (int k = 0; k < 4; k++) {
                float gx = A1[0][0][k] + A1[0][1][k] + A1[0][2][k];
                float gy = A2[0][2][k] - A2[0][0][k];
                float gz = A3[0][0][k] + 2.f * A3[0][1][k] + A3[0][2][k];
                va[k] = sqrtf(gx * gx + gy * gy + gz * gz);
                gx = A1[1][0][k] + A1[1][1][k] + A1[1][2][k];
                gy = A2[1][2][k] - A2[1][0][k];
                gz = A3[1][0][k] + 2.f * A3[1][1][k] + A3[1][2][k];
                vb[k] = sqrtf(gx * gx + gy * gy + gz * gz);
            }
            st_h4(oa, idx, va[0], va[1], va[2], va[3]);
            st_h4(ob, idx, vb[0], vb[1], vb[2], vb[3]);
        }
    }
}

// ---- W+H box sums of 5 moments, 8-wide rolling ------------------------------
// Accumulate directly into S with sign (avoids q[5][8] temp -> lower VGPR).
template <bool NEG>
__device__ __forceinline__ void q5_accum8(const float x[16], const float y[16], float S[5][8]) {
    float s0 = 0, s1 = 0, s2 = 0, s3 = 0, s4 = 0;
#pragma unroll
    for (int j = 0; j < 9; j++) {
        s0 += x[j]; s1 += y[j];
        s2 += x[j] * x[j]; s3 += y[j] * y[j]; s4 += x[j] * y[j];
    }
#pragma unroll
    for (int k = 0; k < 8; k++) {
        if (k) {
            s0 += x[k + 8] - x[k - 1];
            s1 += y[k + 8] - y[k - 1];
            s2 += x[k + 8] * x[k + 8] - x[k - 1] * x[k - 1];
            s3 += y[k + 8] * y[k + 8] - y[k - 1] * y[k - 1];
            s4 += x[k + 8] * y[k + 8] - x[k - 1] * y[k - 1];
        }
        if (NEG) { S[0][k] -= s0; S[1][k] -= s1; S[2][k] -= s2; S[3][k] -= s3; S[4][k] -= s4; }
        else     { S[0][k] += s0; S[1][k] += s1; S[2][k] += s2; S[3][k] += s3; S[4][k] += s4; }
    }
}

// 16-wide window [w-4, w+12) loads. w = w8*8 -> all float4/uint4 16B-aligned.
__device__ __forceinline__ void ld16(const float* __restrict__ p, int rowbase, int w, float x[16]) {
    bool lo = (w >= 4);
    bool hi = (w + 15 < WWW);
    float4 a0 = ldg4(p, rowbase + w - 4, lo);
    float4 a1 = *(const float4*)(p + rowbase + w);
    float4 a2 = *(const float4*)(p + rowbase + w + 4);
    float4 a3 = ldg4(p, rowbase + w + 8, hi);
    x[0] = a0.x; x[1] = a0.y; x[2] = a0.z; x[3] = a0.w;
    x[4] = a1.x; x[5] = a1.y; x[6] = a1.z; x[7] = a1.w;
    x[8] = a2.x; x[9] = a2.y; x[10] = a2.z; x[11] = a2.w;
    x[12] = a3.x; x[13] = a3.y; x[14] = a3.z; x[15] = a3.w;
}

__device__ __forceinline__ void ld16(const __half* __restrict__ p, int rowbase, int w, float x[16]) {
    bool lo = (w >= 4);
    bool hi = (w + 15 < WWW);
    union { __half2 h2[2]; uint2 u; } u0, u3;
    union { __half2 h2[4]; uint4 u; } uc;
    uint2 z2 = make_uint2(0, 0);
    u0.u = lo ? *(const uint2*)(p + rowbase + w - 4) : z2;
    uc.u = *(const uint4*)(p + rowbase + w);  // 16B aligned (w mult of 8)
    u3.u = hi ? *(const uint2*)(p + rowbase + w + 8) : z2;
    x[0] = __low2float(u0.h2[0]); x[1] = __high2float(u0.h2[0]);
    x[2] = __low2float(u0.h2[1]); x[3] = __high2float(u0.h2[1]);
#pragma unroll
    for (int j = 0; j < 4; j++) {
        x[4 + 2 * j] = __low2float(uc.h2[j]);
        x[5 + 2 * j] = __high2float(uc.h2[j]);
    }
    x[12] = __low2float(u3.h2[0]); x[13] = __high2float(u3.h2[0]);
    x[14] = __low2float(u3.h2[1]); x[15] = __high2float(u3.h2[1]);
}

template <typename T, bool NEG>
__device__ __forceinline__ void rowq5_8(const T* __restrict__ a, const T* __restrict__ b,
                                        int rowbase, int w, float S[5][8]) {
    float x[16], y[16];
    ld16(a, rowbase, w, x);
    ld16(b, rowbase, w, y);
    q5_accum8<NEG>(x, y, S);
}

// Output: interleaved tile t ([g][5][4] fp16), two groups per thread.
template <typename T>
__device__ void whsum_body(int t_, const T* __restrict__ a, const T* __restrict__ b,
                           __half* __restrict__ t) {
    int w8 = t_ % W8;
    int w = w8 * 8;
    int d = (t_ / W8) % DD;
    int c = t_ / (W8 * DD);
    int h0 = c * HC;

    float S[5][8] = {{0}};
    for (int j = 0; j < 9; j++) {
        int r = h0 - 4 + j;
        if ((unsigned)r < (unsigned)HHH)
            rowq5_8<T, false>(a, b, (d * HHH + r) * WWW, w, S);
    }
    st_t5x2(t, (d * HHH + h0) * W4 + 2 * w8, S);
    for (int h = h0 + 1; h < h0 + HC; h++) {
        int rin = h + 4, rout = h - 5;
        if (rin < HHH)
            rowq5_8<T, false>(a, b, (d * HHH + rin) * WWW, w, S);
        if (rout >= 0)
            rowq5_8<T, true>(a, b, (d * HHH + rout) * WWW, w, S);
        st_t5x2(t, (d * HHH + h) * W4 + 2 * w8, S);
    }
}

// ---- D box-sum + cc + reduction, 8-wide -------------------------------------
__device__ __forceinline__ float cc1(float s0, float s1, float s2, float s3, float s4) {
    const float wsz = 729.0f;
    const float inv = 1.0f / 729.0f;
    float uI = s0 * inv;
    float uJ = s1 * inv;
    float cross = s4 - uJ * s0 - uI * s1 + uI * uJ * wsz;
    float Iv = s2 - 2.0f * uI * s0 + uI * uI * wsz;
    float Jv = s3 - 2.0f * uJ * s1 + uJ * uJ * wsz;
    return cross * cross / (Iv * Jv + 1e-5f);
}

__device__ void dcc_body(int t_, const __half* __restrict__ tile,
                         double* __restrict__ acc, int pair) {
    int w8 = t_ % W8;
    int h = (t_ / W8) % HHH;
    int c = t_ / (W8 * HHH);
    int d0 = c * DC;

    float S[5][8] = {{0}};
    for (int j = 0; j < 9; j++) {
        int r = d0 - 4 + j;
        if ((unsigned)r < (unsigned)DD) {
            float v[5][8];
            ld_t5x2(tile, (r * HHH + h) * W4 + 2 * w8, v);
#pragma unroll
            for (int q = 0; q < 5; q++)
#pragma unroll
                for (int k = 0; k < 8; k++) S[q][k] += v[q][k];
        }
    }
    float local = 0.f;
#pragma unroll
    for (int k = 0; k < 8; k++) local += cc1(S[0][k], S[1][k], S[2][k], S[3][k], S[4][k]);
#pragma unroll
    for (int d = 1; d < DC; d++) {
        int rin = d0 + d + 4, rout = d0 + d - 5;
        if (rin < DD) {
            float v[5][8];
            ld_t5x2(tile, (rin * HHH + h) * W4 + 2 * w8, v);
#pragma unroll
            for (int q = 0; q < 5; q++)
#pragma unroll
                for (int k = 0; k < 8; k++) S[q][k] += v[q][k];
        }
        if (rout >= 0) {
            float v[5][8];
            ld_t5x2(tile, (rout * HHH + h) * W4 + 2 * w8, v);
#pragma unroll
            for (int q = 0; q < 5; q++)
#pragma unroll
                for (int k = 0; k < 8; k++) S[q][k] -= v[q][k];
        }
#pragma unroll
        for (int k = 0; k < 8; k++) local += cc1(S[0][k], S[1][k], S[2][k], S[3][k], S[4][k]);
    }

    for (int off = 32; off > 0; off >>= 1) local += __shfl_down(local, off);
    __shared__ float wsum_[4];
    if ((threadIdx.x & 63) == 0) wsum_[threadIdx.x >> 6] = local;
    __syncthreads();
    if (threadIdx.x == 0) {
        float s = wsum_[0] + wsum_[1] + wsum_[2] + wsum_[3];
        atomicAdd(&acc[pair], (double)s);
    }
}

// ---- Stage kernels (wide schedule) ------------------------------------------
// S1: fused sobel+lap (both volumes) + whsum_p0 + zero.
__global__ void __launch_bounds__(256, 4)
stage1w(const float* __restrict__ yt, const float* __restrict__ yp,
        __half* __restrict__ e1a, __half* __restrict__ e1b,
        __half* __restrict__ e2a, __half* __restrict__ e2b,
        __half* __restrict__ tA, double* __restrict__ acc) {
    int b = blockIdx.x;
    if (b < NB_FU) {
        int lb = xcd_swz(b, NB_FU);
        fused_body(lb * 256 + threadIdx.x, yt, e1a, e2a);
    } else if (b < 2 * NB_FU) {
        int lb = xcd_swz(b - NB_FU, NB_FU);
        fused_body(lb * 256 + threadIdx.x, yp, e1b, e2b);
    } else if (b < 2 * NB_FU + NB_WH) {
        int lb = xcd_swz(b - 2 * NB_FU, NB_WH);
        whsum_body<float>(lb * 256 + threadIdx.x, yt, yp, tA);
    } else {
        if (threadIdx.x < 3) acc[threadIdx.x] = 0.0;
    }
}

// S2: wh1(e1->tB) + wh2(e2->tC) + dcc0(tA->acc0)
__global__ void stage2m(const __half* __restrict__ e1a, const __half* __restrict__ e1b,
                        const __half* __restrict__ e2a, const __half* __restrict__ e2b,
                        __half* __restrict__ tB, __half* __restrict__ tC,
                        const __half* __restrict__ tA, double* __restrict__ acc) {
    int b = blockIdx.x;
    if (b < NB_WH) {
        int lb = xcd_swz(b, NB_WH);
        whsum_body<__half>(lb * 256 + threadIdx.x, e1a, e1b, tB);
    } else if (b < 2 * NB_WH) {
        int lb = xcd_swz(b - NB_WH, NB_WH);
        whsum_body<__half>(lb * 256 + threadIdx.x, e2a, e2b, tC);
    } else {
        int lb = xcd_swz(b - 2 * NB_WH, NB_DCC);
        dcc_body(lb * 256 + threadIdx.x, tA, acc, 0);
    }
}

// S3: dcc1(tB->acc1) + dcc2(tC->acc2)
__global__ void stage3m(const __half* __restrict__ tB, const __half* __restrict__ tC,
                        double* __restrict__ acc) {
    int b = blockIdx.x;
    if (b < NB_DCC) {
        int lb = xcd_swz(b, NB_DCC);
        dcc_body(lb * 256 + threadIdx.x, tB, acc, 1);
    } else {
        int lb = xcd_swz(b - NB_DCC, NB_DCC);
        dcc_body(lb * 256 + threadIdx.x, tC, acc, 2);
    }
}

// ---- Stage kernels (fallback schedule) --------------------------------------
__global__ void stage1(const float* __restrict__ yt, const float* __restrict__ yp,
                       __half* __restrict__ e1a, __half* __restrict__ e1b,
                       __half* __restrict__ e2a, __half* __restrict__ e2b,
                       __half* __restrict__ tA, double* __restrict__ acc) {
    int b = blockIdx.x;
    if (b < NB_WH) {
        int lb = xcd_swz(b, NB_WH);
        whsum_body<float>(lb * 256 + threadIdx.x, yt, yp, tA);
    } else if (b < NB_WH + NB_SO) {
        int lb = xcd_swz(b - NB_WH, NB_SO);
        sobel_body(lb * 256 + threadIdx.x, yt, yp, e2a, e2b);
    } else if (b < NB_WH + NB_SO + NB_LAP) {
        int lb = xcd_swz(b - NB_WH - NB_SO, NB_LAP);
        lap_body(lb * 256 + threadIdx.x, yt, yp, e1a, e1b);
    } else {
        if (threadIdx.x < 3) acc[threadIdx.x] = 0.0;
    }
}

__global__ void stage23(const __half* __restrict__ ea, const __half* __restrict__ eb,
                        __half* __restrict__ o, const __half* __restrict__ i,
                        double* __restrict__ acc, int pair) {
    int b = blockIdx.x;
    if (b < NB_WH) {
        int lb = xcd_swz(b, NB_WH);
        whsum_body<__half>(lb * 256 + threadIdx.x, ea, eb, o);
    } else {
        int lb = xcd_swz(b - NB_WH, NB_DCC);
        dcc_body(lb * 256 + threadIdx.x, i, acc, pair);
    }
}

__global__ void dcc_k(const __half* __restrict__ tile, double* __restrict__ acc, int pair) {
    int lb = xcd_swz(blockIdx.x, NB_DCC);
    dcc_body(lb * 256 + threadIdx.x, tile, acc, pair);
}

__global__ void finalize_k(const double* __restrict__ acc, float* __restrict__ out) {
    if (threadIdx.x == 0) {
        double v = 0.8 * acc[0] + 0.1 * acc[1] + 0.1 * acc[2];
        out[0] = (float)(-v / (double)NV);
    }
}

extern "C" void kernel_launch(void* const* d_in, const int* in_sizes, int n_in,
                              void* d_out, int out_size, void* d_ws, size_t ws_size,
                              hipStream_t stream) {
    const float* yt = (const float*)d_in[0];
    const float* yp = (const float*)d_in[1];
    float* out = (float*)d_out;

    // ws layout: acc(256B) | e1a e1b e2a e2b | tA(5nv) | tB(5nv) [| tC(5nv)]
    double* acc = (double*)d_ws;
    __half* base = (__half*)((char*)d_ws + 256);
    size_t nv = (size_t)NV;
    __half* e1a = base + 0 * nv;
    __half* e1b = base + 1 * nv;
    __half* e2a = base + 2 * nv;
    __half* e2b = base + 3 * nv;
    __half* tA = base + 4 * nv;   // interleaved 5-moment tile (5*nv halves)
    __half* tB = base + 9 * nv;
    __half* tC = base + 14 * nv;  // wide schedule only

    bool wide = ws_size >= 256 + 19 * nv * sizeof(__half);

    dim3 blk(256);

    if (wide) {
        // S1: fused sobel+lap + whsum_p0 + zero
        hipLaunchKernelGGL(stage1w, dim3(2 * NB_FU + NB_WH + 1), blk, 0, stream,
                           yt, yp, e1a, e1b, e2a, e2b, tA, acc);
        // S2: wh1 + wh2 + dcc0
        hipLaunchKernelGGL(stage2m, dim3(2 * NB_WH + NB_DCC), blk, 0, stream,
                           e1a, e1b, e2a, e2b, tB, tC, tA, acc);
        // S3: dcc1 + dcc2
        hipLaunchKernelGGL(stage3m, dim3(2 * NB_DCC), blk, 0, stream, tB, tC, acc);
    } else {
        // Fallback (2 tile sets)
        hipLaunchKernelGGL(stage1, dim3(NB_WH + NB_SO + NB_LAP + 1), blk, 0, stream,
                           yt, yp, e1a, e1b, e2a, e2b, tA, acc);
        hipLaunchKernelGGL(stage23, dim3(NB_WH + NB_DCC), blk, 0, stream,
                           e1a, e1b, tB, tA, acc, 0);
        hipLaunchKernelGGL(stage23, dim3(NB_WH + NB_DCC), blk, 0, stream,
                           e2a, e2b, tA, tB, acc, 1);
        hipLaunchKernelGGL(dcc_k, dim3(NB_DCC), blk, 0, stream, tA, acc, 2);
    }

    hipLaunchKernelGGL(finalize_k, dim3(1), dim3(1), 0, stream, acc, out);
}

// Round 7
// 534.563 us; speedup vs baseline: 1.0440x; 1.0440x over previous
//
#include <hip/hip_runtime.h>
#include <hip/hip_fp16.h>
#include <math.h>

// Volume dims (1,1,160,192,160) fp32
#define DD 160
#define HHH 192
#define WWW 160
constexpr int HW = HHH * WWW;          // 30720
constexpr int NV = DD * HHH * WWW;     // 4915200
constexpr int W4 = WWW / 4;            // 40 (tile group granularity)
constexpr int W8 = WWW / 8;            // 20 (whsum/dcc thread granularity)
constexpr int HC = 4;                  // whsum H-chunk
constexpr int DC = 4;                  // dcc D-chunk
constexpr int SC = 8;                  // sobel D-chunk (fallback path only)
constexpr int SCF = 4;                 // fused sobel+lap D-chunk

constexpr int NB_WH  = (W8 * DD * (HHH / HC)) / 256;   // 600
constexpr int NB_SO  = (W4 * HHH * (DD / SC)) / 256;   // 600  (fallback)
constexpr int NB_LAP = (NV / 4) / 256;                 // 4800 (fallback)
constexpr int NB_DCC = (W8 * HHH * (DD / DC)) / 256;   // 600
constexpr int NB_FU  = (W4 * HHH * (DD / SCF)) / 256;  // 1200 (per volume)

// Per-phase XCD-chunked swizzle (proven: halves FETCH via L2 locality).
__device__ __forceinline__ int xcd_swz(int b, int n) {
    int q = n >> 3;
    return (b & 7) * q + (b >> 3);
}

__device__ __forceinline__ float4 ldg4(const float* __restrict__ p, int idx, bool ok) {
    float4 z = make_float4(0.f, 0.f, 0.f, 0.f);
    return ok ? *(const float4*)(p + idx) : z;
}

__device__ __forceinline__ void st_h4(__half* __restrict__ t, int idx,
                                      float s0, float s1, float s2, float s3) {
    union { __half2 h2[2]; uint2 u; } pk;
    pk.h2[0] = __floats2half2_rn(s0, s1);
    pk.h2[1] = __floats2half2_rn(s2, s3);
    *(uint2*)(t + idx) = pk.u;  // idx%4==0 -> 8B aligned
}

// ---- Interleaved 5-moment tile: group g (4 voxels) = [5][4] fp16 = 40B.
// w8 thread handles two adjacent groups = 80B contiguous = 5x uint4.
// SCRATCH-FREE pack/unpack (R6 lesson: address-taken local array -> scratch
// spill, +53MB WRITE, 1.7x regression). All indices static; named unions only.
// Layout: half index = (k>>2)*20 + q*4 + (k&3). uint4 j covers 8j..8j+7:
//   j0: S[0][0..3] S[1][0..3] | j1: S[2][0..3] S[3][0..3]
//   j2: S[4][0..3] S[0][4..7] | j3: S[1][4..7] S[2][4..7] | j4: S[3][4..7] S[4][4..7]
union U4 { __half2 h2[4]; uint4 u; };

__device__ __forceinline__ void st_t5x2(__half* __restrict__ t, int g2, const float S[5][8]) {
    __half* p = t + (size_t)g2 * 20;
    U4 a, b, c, d, e;
    a.h2[0] = __floats2half2_rn(S[0][0], S[0][1]); a.h2[1] = __floats2half2_rn(S[0][2], S[0][3]);
    a.h2[2] = __floats2half2_rn(S[1][0], S[1][1]); a.h2[3] = __floats2half2_rn(S[1][2], S[1][3]);
    b.h2[0] = __floats2half2_rn(S[2][0], S[2][1]); b.h2[1] = __floats2half2_rn(S[2][2], S[2][3]);
    b.h2[2] = __floats2half2_rn(S[3][0], S[3][1]); b.h2[3] = __floats2half2_rn(S[3][2], S[3][3]);
    c.h2[0] = __floats2half2_rn(S[4][0], S[4][1]); c.h2[1] = __floats2half2_rn(S[4][2], S[4][3]);
    c.h2[2] = __floats2half2_rn(S[0][4], S[0][5]); c.h2[3] = __floats2half2_rn(S[0][6], S[0][7]);
    d.h2[0] = __floats2half2_rn(S[1][4], S[1][5]); d.h2[1] = __floats2half2_rn(S[1][6], S[1][7]);
    d.h2[2] = __floats2half2_rn(S[2][4], S[2][5]); d.h2[3] = __floats2half2_rn(S[2][6], S[2][7]);
    e.h2[0] = __floats2half2_rn(S[3][4], S[3][5]); e.h2[1] = __floats2half2_rn(S[3][6], S[3][7]);
    e.h2[2] = __floats2half2_rn(S[4][4], S[4][5]); e.h2[3] = __floats2half2_rn(S[4][6], S[4][7]);
    *(uint4*)(p +  0) = a.u;
    *(uint4*)(p +  8) = b.u;
    *(uint4*)(p + 16) = c.u;
    *(uint4*)(p + 24) = d.u;
    *(uint4*)(p + 32) = e.u;
}

__device__ __forceinline__ void ld_t5x2(const __half* __restrict__ t, int g2, float v[5][8]) {
    const __half* p = t + (size_t)g2 * 20;
    U4 a, b, c, d, e;
    a.u = *(const uint4*)(p +  0);
    b.u = *(const uint4*)(p +  8);
    c.u = *(const uint4*)(p + 16);
    d.u = *(const uint4*)(p + 24);
    e.u = *(const uint4*)(p + 32);
    v[0][0] = __low2float(a.h2[0]); v[0][1] = __high2float(a.h2[0]);
    v[0][2] = __low2float(a.h2[1]); v[0][3] = __high2float(a.h2[1]);
    v[1][0] = __low2float(a.h2[2]); v[1][1] = __high2float(a.h2[2]);
    v[1][2] = __low2float(a.h2[3]); v[1][3] = __high2float(a.h2[3]);
    v[2][0] = __low2float(b.h2[0]); v[2][1] = __high2float(b.h2[0]);
    v[2][2] = __low2float(b.h2[1]); v[2][3] = __high2float(b.h2[1]);
    v[3][0] = __low2float(b.h2[2]); v[3][1] = __high2float(b.h2[2]);
    v[3][2] = __low2float(b.h2[3]); v[3][3] = __high2float(b.h2[3]);
    v[4][0] = __low2float(c.h2[0]); v[4][1] = __high2float(c.h2[0]);
    v[4][2] = __low2float(c.h2[1]); v[4][3] = __high2float(c.h2[1]);
    v[0][4] = __low2float(c.h2[2]); v[0][5] = __high2float(c.h2[2]);
    v[0][6] = __low2float(c.h2[3]); v[0][7] = __high2float(c.h2[3]);
    v[1][4] = __low2float(d.h2[0]); v[1][5] = __high2float(d.h2[0]);
    v[1][6] = __low2float(d.h2[1]); v[1][7] = __high2float(d.h2[1]);
    v[2][4] = __low2float(d.h2[2]); v[2][5] = __high2float(d.h2[2]);
    v[2][6] = __low2float(d.h2[3]); v[2][7] = __high2float(d.h2[3]);
    v[3][4] = __low2float(e.h2[0]); v[3][5] = __high2float(e.h2[0]);
    v[3][6] = __low2float(e.h2[1]); v[3][7] = __high2float(e.h2[1]);
    v[4][4] = __low2float(e.h2[2]); v[4][5] = __high2float(e.h2[2]);
    v[4][6] = __low2float(e.h2[3]); v[4][7] = __high2float(e.h2[3]);
}

// ---- Fused sobel+lap body, ONE volume per thread (4-wide, unchanged) -------
__device__ void fused_body(int t, const float* __restrict__ p,
                           __half* __restrict__ olap, __half* __restrict__ osob) {
    int w = (t % W4) * 4;
    int h = (t / W4) % HHH;
    int c = t / (W4 * HHH);
    int d0 = c * SCF;

    float A1[3][4], A2[3][4], A3[3][4];
    float P6[6], PP4[4], PH[4];
#pragma unroll
    for (int j = 0; j < 3; j++)
#pragma unroll
        for (int k = 0; k < 4; k++) { A1[j][k] = 0.f; A2[j][k] = 0.f; A3[j][k] = 0.f; }
#pragma unroll
    for (int k = 0; k < 6; k++) P6[k] = 0.f;
#pragma unroll
    for (int k = 0; k < 4; k++) { PP4[k] = 0.f; PH[k] = 0.f; }

#pragma unroll
    for (int i = 0; i < SCF + 2; i++) {
        int s = d0 - 1 + i;
#pragma unroll
        for (int k = 0; k < 4; k++) {
            A1[0][k] = A1[1][k]; A2[0][k] = A2[1][k]; A3[0][k] = A3[1][k];
            A1[1][k] = A1[2][k]; A2[1][k] = A2[2][k]; A3[1][k] = A3[2][k];
        }
        float C6[6] = {0.f, 0.f, 0.f, 0.f, 0.f, 0.f};
        float CH[4] = {0.f, 0.f, 0.f, 0.f};
#pragma unroll
        for (int k = 0; k < 4; k++) { A1[2][k] = 0.f; A2[2][k] = 0.f; A3[2][k] = 0.f; }
        if (s >= 0 && s < DD) {
#pragma unroll
            for (int kh = -1; kh <= 1; kh++) {
                int h2 = h + kh;
                if ((unsigned)h2 < (unsigned)HHH) {
                    int rb = (s * HHH + h2) * WWW + w;
                    float4 cen = *(const float4*)(p + rb);
                    float xm = (w > 0) ? p[rb - 1] : 0.f;
                    float xp = (w + 4 < WWW) ? p[rb + 4] : 0.f;
                    float xv[6] = {xm, cen.x, cen.y, cen.z, cen.w, xp};
                    float smh = (kh == 0) ? 2.f : 1.f;
                    float grh = (float)kh;
#pragma unroll
                    for (int k = 0; k < 4; k++) {
                        float gw = xv[k + 2] - xv[k];
                        float pw = xv[k] + xv[k + 1] + xv[k + 2];
                        float sw = pw + xv[k + 1];
                        A1[2][k] += smh * gw;
                        A2[2][k] += sw;
                        A3[2][k] += grh * pw;
                    }
                    if (kh == 0) {
#pragma unroll
                        for (int j = 0; j < 6; j++) C6[j] = xv[j];
                    } else {
#pragma unroll
                        for (int k = 0; k < 4; k++) CH[k] += xv[k + 1];
                    }
                }
            }
        }
        if (i >= 2) {
            int d = s - 1;
            int idx = (d * HHH + h) * WWW + w;
            float vs[4], vl[4];
#pragma unroll
            for (int k = 0; k < 4; k++) {
                float gx = A1[0][k] + A1[1][k] + A1[2][k];
                float gy = A2[2][k] - A2[0][k];
                float gz = A3[0][k] + 2.f * A3[1][k] + A3[2][k];
                vs[k] = sqrtf(gx * gx + gy * gy + gz * gz);
                vl[k] = 6.f * P6[k + 1] - (P6[k] + P6[k + 2] + PH[k] + PP4[k] + C6[k + 1]);
            }
            st_h4(osob, idx, vs[0], vs[1], vs[2], vs[3]);
            st_h4(olap, idx, vl[0], vl[1], vl[2], vl[3]);
        }
#pragma unroll
        for (int k = 0; k < 4; k++) PP4[k] = P6[k + 1];
#pragma unroll
        for (int j = 0; j < 6; j++) P6[j] = C6[j];
#pragma unroll
        for (int k = 0; k < 4; k++) PH[k] = CH[k];
    }
}

// ---- Laplacian body (fallback path only) -----------------------------------
__device__ __forceinline__ void lap_body(int t, const float* __restrict__ a,
                                         const float* __restrict__ b,
                                         __half* __restrict__ oa, __half* __restrict__ ob) {
    int w = (t % W4) * 4;
    int h = (t / W4) % HHH;
    int d = t / (W4 * HHH);
    int idx = (d * HHH + h) * WWW + w;
    bool dok0 = d > 0, dok1 = d < DD - 1, hok0 = h > 0, hok1 = h < HHH - 1;
#pragma unroll
    for (int s = 0; s < 2; s++) {
        const float* p = s ? b : a;
        __half* o = s ? ob : oa;
        float4 c = *(const float4*)(p + idx);
        float m1 = (w > 0) ? p[idx - 1] : 0.f;
        float p4 = (w + 4 < WWW) ? p[idx + 4] : 0.f;
        float4 dm = ldg4(p, idx - HW, dok0);
        float4 dp = ldg4(p, idx + HW, dok1);
        float4 hm = ldg4(p, idx - WWW, hok0);
        float4 hp = ldg4(p, idx + WWW, hok1);
        st_h4(o, idx,
              6.f * c.x - (m1 + c.y + dm.x + dp.x + hm.x + hp.x),
              6.f * c.y - (c.x + c.z + dm.y + dp.y + hm.y + hp.y),
              6.f * c.z - (c.y + c.w + dm.z + dp.z + hm.z + hp.z),
              6.f * c.w - (c.z + p4 + dm.w + dp.w + hm.w + hp.w));
    }
}

// ---- Sobel body (fallback path only) ----------------------------------------
__device__ __forceinline__ void sobel_slice(const float* __restrict__ p, int s, int h, int w,
                                            float a1[4], float a2[4], float a3[4]) {
#pragma unroll
    for (int k = 0; k < 4; k++) { a1[k] = 0.f; a2[k] = 0.f; a3[k] = 0.f; }
#pragma unroll
    for (int kh = -1; kh <= 1; kh++) {
        int h2 = h + kh;
        if ((unsigned)h2 < (unsigned)HHH) {
            int rb = (s * HHH + h2) * WWW + w;
            float4 cen = *(const float4*)(p + rb);
            float xm = (w > 0) ? p[rb - 1] : 0.f;
            float xp = (w + 4 < WWW) ? p[rb + 4] : 0.f;
            float xv[6] = {xm, cen.x, cen.y, cen.z, cen.w, xp};
            float smh = (kh == 0) ? 2.f : 1.f;
            float grh = (float)kh;
#pragma unroll
            for (int k = 0; k < 4; k++) {
                float gw = xv[k + 2] - xv[k];
                float pw = xv[k] + xv[k + 1] + xv[k + 2];
                float sw = pw + xv[k + 1];
                a1[k] += smh * gw;
                a2[k] += sw;
                a3[k] += grh * pw;
            }
        }
    }
}

__device__ __forceinline__ void sobel_body(int t, const float* __restrict__ a,
                                           const float* __restrict__ b,
                                           __half* __restrict__ oa, __half* __restrict__ ob) {
    int w = (t % W4) * 4;
    int h = (t / W4) % HHH;
    int c = t / (W4 * HHH);
    int d0 = c * SC;

    float A1[2][3][4], A2[2][3][4], A3[2][3][4];
#pragma unroll
    for (int r = 0; r < 2; r++)
#pragma unroll
        for (int j = 0; j < 3; j++)
#pragma unroll
            for (int k = 0; k < 4; k++) { A1[r][j][k] = 0.f; A2[r][j][k] = 0.f; A3[r][j][k] = 0.f; }

#pragma unroll
    for (int i = 0; i < SC + 2; i++) {
        int s = d0 - 1 + i;
#pragma unroll
        for (int r = 0; r < 2; r++)
#pragma unroll
            for (int k = 0; k < 4; k++) {
                A1[r][0][k] = A1[r][1][k]; A2[r][0][k] = A2[r][1][k]; A3[r][0][k] = A3[r][1][k];
                A1[r][1][k] = A1[r][2][k]; A2[r][1][k] = A2[r][2][k]; A3[r][1][k] = A3[r][2][k];
            }
        if (s >= 0 && s < DD) {
            sobel_slice(a, s, h, w, A1[0][2], A2[0][2], A3[0][2]);
            sobel_slice(b, s, h, w, A1[1][2], A2[1][2], A3[1][2]);
        } else {
#pragma unroll
            for (int r = 0; r < 2; r++)
#pragma unroll
                for (int k = 0; k < 4; k++) { A1[r][2][k] = 0.f; A2[r][2][k] = 0.f; A3[r][2][k] = 0.f; }
        }
        if (i >= 2) {
            int d = s - 1;
            int idx = (d * HHH + h) * WWW + w;
            float va[4], vb[4];
#pragma unroll
            for (int k = 0; k < 4; k++) {
                float gx = A1[0][0][k] + A1[0][1][k] + A1[0][2][k];
                float gy = A2[0][2][k] - A2[0][0][k];
                float gz = A3[0][0][k] + 2.f * A3[0][1][k] + A3[0][2][k];
                va[k] = sqrtf(gx * gx + gy * gy + gz * gz);
                gx = A1[1][0][k] + A1[1][1][k] + A1[1][2][k];
                gy = A2[1][2][k] - A2[1][0][k];
                gz = A3[1][0][k] + 2.f * A3[1][1][k] + A3[1][2][k];
                vb[k] = sqrtf(gx * gx + gy * gy + gz * gz);
            }
            st_h4(oa, idx, va[0], va[1], va[2], va[3]);
            st_h4(ob, idx, vb[0], vb[1], vb[2], vb[3]);
        }
    }
}

// ---- W+H box sums of 5 moments, 8-wide rolling ------------------------------
template <bool NEG>
__device__ __forceinline__ void q5_accum8(const float x[16], const float y[16], float S[5][8]) {
    float s0 = 0, s1 = 0, s2 = 0, s3 = 0, s4 = 0;
#pragma unroll
    for (int j = 0; j < 9; j++) {
        s0 += x[j]; s1 += y[j];
        s2 += x[j] * x[j]; s3 += y[j] * y[j]; s4 += x[j] * y[j];
    }
#pragma unroll
    for (int k = 0; k < 8; k++) {
        if (k) {
            s0 += x[k + 8] - x[k - 1];
            s1 += y[k + 8] - y[k - 1];
            s2 += x[k + 8] * x[k + 8] - x[k - 1] * x[k - 1];
            s3 += y[k + 8] * y[k + 8] - y[k - 1] * y[k - 1];
            s4 += x[k + 8] * y[k + 8] - x[k - 1] * y[k - 1];
        }
        if (NEG) { S[0][k] -= s0; S[1][k] -= s1; S[2][k] -= s2; S[3][k] -= s3; S[4][k] -= s4; }
        else     { S[0][k] += s0; S[1][k] += s1; S[2][k] += s2; S[3][k] += s3; S[4][k] += s4; }
    }
}

// 16-wide window [w-4, w+12) loads. w = w8*8 -> all float4/uint4 16B-aligned.
__device__ __forceinline__ void ld16(const float* __restrict__ p, int rowbase, int w, float x[16]) {
    bool lo = (w >= 4);
    bool hi = (w + 15 < WWW);
    float4 a0 = ldg4(p, rowbase + w - 4, lo);
    float4 a1 = *(const float4*)(p + rowbase + w);
    float4 a2 = *(const float4*)(p + rowbase + w + 4);
    float4 a3 = ldg4(p, rowbase + w + 8, hi);
    x[0] = a0.x; x[1] = a0.y; x[2] = a0.z; x[3] = a0.w;
    x[4] = a1.x; x[5] = a1.y; x[6] = a1.z; x[7] = a1.w;
    x[8] = a2.x; x[9] = a2.y; x[10] = a2.z; x[11] = a2.w;
    x[12] = a3.x; x[13] = a3.y; x[14] = a3.z; x[15] = a3.w;
}

__device__ __forceinline__ void ld16(const __half* __restrict__ p, int rowbase, int w, float x[16]) {
    bool lo = (w >= 4);
    bool hi = (w + 15 < WWW);
    union { __half2 h2[2]; uint2 u; } u0, u3;
    union { __half2 h2[4]; uint4 u; } uc;
    uint2 z2 = make_uint2(0, 0);
    u0.u = lo ? *(const uint2*)(p + rowbase + w - 4) : z2;
    uc.u = *(const uint4*)(p + rowbase + w);  // 16B aligned (w mult of 8)
    u3.u = hi ? *(const uint2*)(p + rowbase + w + 8) : z2;
    x[0] = __low2float(u0.h2[0]); x[1] = __high2float(u0.h2[0]);
    x[2] = __low2float(u0.h2[1]); x[3] = __high2float(u0.h2[1]);
#pragma unroll
    for (int j = 0; j < 4; j++) {
        x[4 + 2 * j] = __low2float(uc.h2[j]);
        x[5 + 2 * j] = __high2float(uc.h2[j]);
    }
    x[12] = __low2float(u3.h2[0]); x[13] = __high2float(u3.h2[0]);
    x[14] = __low2float(u3.h2[1]); x[15] = __high2float(u3.h2[1]);
}

template <typename T, bool NEG>
__device__ __forceinline__ void rowq5_8(const T* __restrict__ a, const T* __restrict__ b,
                                        int rowbase, int w, float S[5][8]) {
    float x[16], y[16];
    ld16(a, rowbase, w, x);
    ld16(b, rowbase, w, y);
    q5_accum8<NEG>(x, y, S);
}

// Output: interleaved tile t ([g][5][4] fp16), two groups per thread.
template <typename T>
__device__ void whsum_body(int t_, const T* __restrict__ a, const T* __restrict__ b,
                           __half* __restrict__ t) {
    int w8 = t_ % W8;
    int w = w8 * 8;
    int d = (t_ / W8) % DD;
    int c = t_ / (W8 * DD);
    int h0 = c * HC;

    float S[5][8] = {{0}};
    for (int j = 0; j < 9; j++) {
        int r = h0 - 4 + j;
        if ((unsigned)r < (unsigned)HHH)
            rowq5_8<T, false>(a, b, (d * HHH + r) * WWW, w, S);
    }
    st_t5x2(t, (d * HHH + h0) * W4 + 2 * w8, S);
    for (int h = h0 + 1; h < h0 + HC; h++) {
        int rin = h + 4, rout = h - 5;
        if (rin < HHH)
            rowq5_8<T, false>(a, b, (d * HHH + rin) * WWW, w, S);
        if (rout >= 0)
            rowq5_8<T, true>(a, b, (d * HHH + rout) * WWW, w, S);
        st_t5x2(t, (d * HHH + h) * W4 + 2 * w8, S);
    }
}

// ---- D box-sum + cc + reduction, 8-wide -------------------------------------
__device__ __forceinline__ float cc1(float s0, float s1, float s2, float s3, float s4) {
    const float wsz = 729.0f;
    const float inv = 1.0f / 729.0f;
    float uI = s0 * inv;
    float uJ = s1 * inv;
    float cross = s4 - uJ * s0 - uI * s1 + uI * uJ * wsz;
    float Iv = s2 - 2.0f * uI * s0 + uI * uI * wsz;
    float Jv = s3 - 2.0f * uJ * s1 + uJ * uJ * wsz;
    return cross * cross / (Iv * Jv + 1e-5f);
}

__device__ void dcc_body(int t_, const __half* __restrict__ tile,
                         double* __restrict__ acc, int pair) {
    int w8 = t_ % W8;
    int h = (t_ / W8) % HHH;
    int c = t_ / (W8 * HHH);
    int d0 = c * DC;

    float S[5][8] = {{0}};
    for (int j = 0; j < 9; j++) {
        int r = d0 - 4 + j;
        if ((unsigned)r < (unsigned)DD) {
            float v[5][8];
            ld_t5x2(tile, (r * HHH + h) * W4 + 2 * w8, v);
#pragma unroll
            for (int q = 0; q < 5; q++)
#pragma unroll
                for (int k = 0; k < 8; k++) S[q][k] += v[q][k];
        }
    }
    float local = 0.f;
#pragma unroll
    for (int k = 0; k < 8; k++) local += cc1(S[0][k], S[1][k], S[2][k], S[3][k], S[4][k]);
#pragma unroll
    for (int d = 1; d < DC; d++) {
        int rin = d0 + d + 4, rout = d0 + d - 5;
        if (rin < DD) {
            float v[5][8];
            ld_t5x2(tile, (rin * HHH + h) * W4 + 2 * w8, v);
#pragma unroll
            for (int q = 0; q < 5; q++)
#pragma unroll
                for (int k = 0; k < 8; k++) S[q][k] += v[q][k];
        }
        if (rout >= 0) {
            float v[5][8];
            ld_t5x2(tile, (rout * HHH + h) * W4 + 2 * w8, v);
#pragma unroll
            for (int q = 0; q < 5; q++)
#pragma unroll
                for (int k = 0; k < 8; k++) S[q][k] -= v[q][k];
        }
#pragma unroll
        for (int k = 0; k < 8; k++) local += cc1(S[0][k], S[1][k], S[2][k], S[3][k], S[4][k]);
    }

    for (int off = 32; off > 0; off >>= 1) local += __shfl_down(local, off);
    __shared__ float wsum_[4];
    if ((threadIdx.x & 63) == 0) wsum_[threadIdx.x >> 6] = local;
    __syncthreads();
    if (threadIdx.x == 0) {
        float s = wsum_[0] + wsum_[1] + wsum_[2] + wsum_[3];
        atomicAdd(&acc[pair], (double)s);
    }
}

// ---- Stage kernels (wide schedule) ------------------------------------------
// S1: fused sobel+lap (both volumes) + whsum_p0 + zero.
__global__ void __launch_bounds__(256, 4)
stage1w(const float* __restrict__ yt, const float* __restrict__ yp,
        __half* __restrict__ e1a, __half* __restrict__ e1b,
        __half* __restrict__ e2a, __half* __restrict__ e2b,
        __half* __restrict__ tA, double* __restrict__ acc) {
    int b = blockIdx.x;
    if (b < NB_FU) {
        int lb = xcd_swz(b, NB_FU);
        fused_body(lb * 256 + threadIdx.x, yt, e1a, e2a);
    } else if (b < 2 * NB_FU) {
        int lb = xcd_swz(b - NB_FU, NB_FU);
        fused_body(lb * 256 + threadIdx.x, yp, e1b, e2b);
    } else if (b < 2 * NB_FU + NB_WH) {
        int lb = xcd_swz(b - 2 * NB_FU, NB_WH);
        whsum_body<float>(lb * 256 + threadIdx.x, yt, yp, tA);
    } else {
        if (threadIdx.x < 3) acc[threadIdx.x] = 0.0;
    }
}

// S2: wh1(e1->tB) + wh2(e2->tC) + dcc0(tA->acc0)
__global__ void stage2m(const __half* __restrict__ e1a, const __half* __restrict__ e1b,
                        const __half* __restrict__ e2a, const __half* __restrict__ e2b,
                        __half* __restrict__ tB, __half* __restrict__ tC,
                        const __half* __restrict__ tA, double* __restrict__ acc) {
    int b = blockIdx.x;
    if (b < NB_WH) {
        int lb = xcd_swz(b, NB_WH);
        whsum_body<__half>(lb * 256 + threadIdx.x, e1a, e1b, tB);
    } else if (b < 2 * NB_WH) {
        int lb = xcd_swz(b - NB_WH, NB_WH);
        whsum_body<__half>(lb * 256 + threadIdx.x, e2a, e2b, tC);
    } else {
        int lb = xcd_swz(b - 2 * NB_WH, NB_DCC);
        dcc_body(lb * 256 + threadIdx.x, tA, acc, 0);
    }
}

// S3: dcc1(tB->acc1) + dcc2(tC->acc2)
__global__ void stage3m(const __half* __restrict__ tB, const __half* __restrict__ tC,
                        double* __restrict__ acc) {
    int b = blockIdx.x;
    if (b < NB_DCC) {
        int lb = xcd_swz(b, NB_DCC);
        dcc_body(lb * 256 + threadIdx.x, tB, acc, 1);
    } else {
        int lb = xcd_swz(b - NB_DCC, NB_DCC);
        dcc_body(lb * 256 + threadIdx.x, tC, acc, 2);
    }
}

// ---- Stage kernels (fallback schedule) --------------------------------------
__global__ void stage1(const float* __restrict__ yt, const float* __restrict__ yp,
                       __half* __restrict__ e1a, __half* __restrict__ e1b,
                       __half* __restrict__ e2a, __half* __restrict__ e2b,
                       __half* __restrict__ tA, double* __restrict__ acc) {
    int b = blockIdx.x;
    if (b < NB_WH) {
        int lb = xcd_swz(b, NB_WH);
        whsum_body<float>(lb * 256 + threadIdx.x, yt, yp, tA);
    } else if (b < NB_WH + NB_SO) {
        int lb = xcd_swz(b - NB_WH, NB_SO);
        sobel_body(lb * 256 + threadIdx.x, yt, yp, e2a, e2b);
    } else if (b < NB_WH + NB_SO + NB_LAP) {
        int lb = xcd_swz(b - NB_WH - NB_SO, NB_LAP);
        lap_body(lb * 256 + threadIdx.x, yt, yp, e1a, e1b);
    } else {
        if (threadIdx.x < 3) acc[threadIdx.x] = 0.0;
    }
}

__global__ void stage23(const __half* __restrict__ ea, const __half* __restrict__ eb,
                        __half* __restrict__ o, const __half* __restrict__ i,
                        double* __restrict__ acc, int pair) {
    int b = blockIdx.x;
    if (b < NB_WH) {
        int lb = xcd_swz(b, NB_WH);
        whsum_body<__half>(lb * 256 + threadIdx.x, ea, eb, o);
    } else {
        int lb = xcd_swz(b - NB_WH, NB_DCC);
        dcc_body(lb * 256 + threadIdx.x, i, acc, pair);
    }
}

__global__ void dcc_k(const __half* __restrict__ tile, double* __restrict__ acc, int pair) {
    int lb = xcd_swz(blockIdx.x, NB_DCC);
    dcc_body(lb * 256 + threadIdx.x, tile, acc, pair);
}

__global__ void finalize_k(const double* __restrict__ acc, float* __restrict__ out) {
    if (threadIdx.x == 0) {
        double v = 0.8 * acc[0] + 0.1 * acc[1] + 0.1 * acc[2];
        out[0] = (float)(-v / (double)NV);
    }
}

extern "C" void kernel_launch(void* const* d_in, const int* in_sizes, int n_in,
                              void* d_out, int out_size, void* d_ws, size_t ws_size,
                              hipStream_t stream) {
    const float* yt = (const float*)d_in[0];
    const float* yp = (const float*)d_in[1];
    float* out = (float*)d_out;

    // ws layout: acc(256B) | e1a e1b e2a e2b | tA(5nv) | tB(5nv) [| tC(5nv)]
    double* acc = (double*)d_ws;
    __half* base = (__half*)((char*)d_ws + 256);
    size_t nv = (size_t)NV;
    __half* e1a = base + 0 * nv;
    __half* e1b = base + 1 * nv;
    __half* e2a = base + 2 * nv;
    __half* e2b = base + 3 * nv;
    __half* tA = base + 4 * nv;   // interleaved 5-moment tile (5*nv halves)
    __half* tB = base + 9 * nv;
    __half* tC = base + 14 * nv;  // wide schedule only

    bool wide = ws_size >= 256 + 19 * nv * sizeof(__half);

    dim3 blk(256);

    if (wide) {
        // S1: fused sobel+lap + whsum_p0 + zero
        hipLaunchKernelGGL(stage1w, dim3(2 * NB_FU + NB_WH + 1), blk, 0, stream,
                           yt, yp, e1a, e1b, e2a, e2b, tA, acc);
        // S2: wh1 + wh2 + dcc0
        hipLaunchKernelGGL(stage2m, dim3(2 * NB_WH + NB_DCC), blk, 0, stream,
                           e1a, e1b, e2a, e2b, tB, tC, tA, acc);
        // S3: dcc1 + dcc2
        hipLaunchKernelGGL(stage3m, dim3(2 * NB_DCC), blk, 0, stream, tB, tC, acc);
    } else {
        // Fallback (2 tile sets)
        hipLaunchKernelGGL(stage1, dim3(NB_WH + NB_SO + NB_LAP + 1), blk, 0, stream,
                           yt, yp, e1a, e1b, e2a, e2b, tA, acc);
        hipLaunchKernelGGL(stage23, dim3(NB_WH + NB_DCC), blk, 0, stream,
                           e1a, e1b, tB, tA, acc, 0);
        hipLaunchKernelGGL(stage23, dim3(NB_WH + NB_DCC), blk, 0, stream,
                           e2a, e2b, tA, tB, acc, 1);
        hipLaunchKernelGGL(dcc_k, dim3(NB_DCC), blk, 0, stream, tA, acc, 2);
    }

    hipLaunchKernelGGL(finalize_k, dim3(1), dim3(1), 0, stream, acc, out);
}

// Round 8
// 335.696 us; speedup vs baseline: 1.6625x; 1.5924x over previous
//
#include <hip/hip_runtime.h>
#include <hip/hip_fp16.h>
#include <math.h>

// Volume dims (1,1,160,192,160) fp32
// R8 = verbatim revert to R5 (session-best, 333 us measured).
// 8-wide variants (R1/R6/R7) all spill: hipcc pins these kernels at 64 VGPR
// and spills past ~64 live floats, even with __launch_bounds__ allowing 128.
// 4-wide bodies (S[5][4] + 24f window) are the widest spill-free config.
#define DD 160
#define HHH 192
#define WWW 160
constexpr int HW = HHH * WWW;          // 30720
constexpr int NV = DD * HHH * WWW;     // 4915200
constexpr int W4 = WWW / 4;            // 40
constexpr int HC = 4;                  // whsum H-chunk (measured best)
constexpr int DC = 4;                  // dcc D-chunk (measured best; 8 regressed)
constexpr int SC = 8;                  // sobel D-chunk (fallback path only)
constexpr int SCF = 4;                 // fused sobel+lap D-chunk

constexpr int NB_WH  = (W4 * DD * (HHH / HC)) / 256;   // 1200
constexpr int NB_SO  = (W4 * HHH * (DD / SC)) / 256;   // 600  (fallback)
constexpr int NB_LAP = (NV / 4) / 256;                 // 4800 (fallback)
constexpr int NB_DCC = (W4 * HHH * (DD / DC)) / 256;   // 1200
constexpr int NB_FU  = (W4 * HHH * (DD / SCF)) / 256;  // 1200 (per volume)

// Per-phase XCD-chunked swizzle (proven: halves FETCH via L2 locality).
// Valid bijection when n % 8 == 0 (all phase ranges here are).
__device__ __forceinline__ int xcd_swz(int b, int n) {
    int q = n >> 3;
    return (b & 7) * q + (b >> 3);
}

__device__ __forceinline__ float4 ldg4(const float* __restrict__ p, int idx, bool ok) {
    float4 z = make_float4(0.f, 0.f, 0.f, 0.f);
    return ok ? *(const float4*)(p + idx) : z;
}

__device__ __forceinline__ void st_h4(__half* __restrict__ t, int idx,
                                      float s0, float s1, float s2, float s3) {
    union { __half2 h2[2]; uint2 u; } pk;
    pk.h2[0] = __floats2half2_rn(s0, s1);
    pk.h2[1] = __floats2half2_rn(s2, s3);
    *(uint2*)(t + idx) = pk.u;  // idx%4==0 -> 8B aligned
}

// ---- Interleaved 5-moment tile: group g holds [5][4] fp16 = 40B contiguous.
// A wave's 64 lanes write 2560B contiguous -> full 128B lines, no RMW.
__device__ __forceinline__ void st_t5(__half* __restrict__ t, int g, const float S[5][4]) {
    __half* p = t + (size_t)g * 20;
#pragma unroll
    for (int q = 0; q < 5; q++) {
        union { __half2 h2[2]; uint2 u; } pk;
        pk.h2[0] = __floats2half2_rn(S[q][0], S[q][1]);
        pk.h2[1] = __floats2half2_rn(S[q][2], S[q][3]);
        *(uint2*)(p + q * 4) = pk.u;  // 40B-aligned base, +8B steps
    }
}

__device__ __forceinline__ void ld_t5(const __half* __restrict__ t, int g, float v[5][4]) {
    const __half* p = t + (size_t)g * 20;
#pragma unroll
    for (int q = 0; q < 5; q++) {
        union { __half2 h2[2]; uint2 u; } pk;
        pk.u = *(const uint2*)(p + q * 4);
        v[q][0] = __low2float(pk.h2[0]); v[q][1] = __high2float(pk.h2[0]);
        v[q][2] = __low2float(pk.h2[1]); v[q][3] = __high2float(pk.h2[1]);
    }
}

// ---- Fused sobel+lap body, ONE volume per thread ---------------------------
__device__ void fused_body(int t, const float* __restrict__ p,
                           __half* __restrict__ olap, __half* __restrict__ osob) {
    int w = (t % W4) * 4;
    int h = (t / W4) % HHH;
    int c = t / (W4 * HHH);
    int d0 = c * SCF;

    float A1[3][4], A2[3][4], A3[3][4];
    float P6[6], PP4[4], PH[4];
#pragma unroll
    for (int j = 0; j < 3; j++)
#pragma unroll
        for (int k = 0; k < 4; k++) { A1[j][k] = 0.f; A2[j][k] = 0.f; A3[j][k] = 0.f; }
#pragma unroll
    for (int k = 0; k < 6; k++) P6[k] = 0.f;
#pragma unroll
    for (int k = 0; k < 4; k++) { PP4[k] = 0.f; PH[k] = 0.f; }

#pragma unroll
    for (int i = 0; i < SCF + 2; i++) {
        int s = d0 - 1 + i;
#pragma unroll
        for (int k = 0; k < 4; k++) {
            A1[0][k] = A1[1][k]; A2[0][k] = A2[1][k]; A3[0][k] = A3[1][k];
            A1[1][k] = A1[2][k]; A2[1][k] = A2[2][k]; A3[1][k] = A3[2][k];
        }
        float C6[6] = {0.f, 0.f, 0.f, 0.f, 0.f, 0.f};
        float CH[4] = {0.f, 0.f, 0.f, 0.f};
#pragma unroll
        for (int k = 0; k < 4; k++) { A1[2][k] = 0.f; A2[2][k] = 0.f; A3[2][k] = 0.f; }
        if (s >= 0 && s < DD) {
#pragma unroll
            for (int kh = -1; kh <= 1; kh++) {
                int h2 = h + kh;
                if ((unsigned)h2 < (unsigned)HHH) {
                    int rb = (s * HHH + h2) * WWW + w;
                    float4 cen = *(const float4*)(p + rb);
                    float xm = (w > 0) ? p[rb - 1] : 0.f;
                    float xp = (w + 4 < WWW) ? p[rb + 4] : 0.f;
                    float xv[6] = {xm, cen.x, cen.y, cen.z, cen.w, xp};
                    float smh = (kh == 0) ? 2.f : 1.f;
                    float grh = (float)kh;
#pragma unroll
                    for (int k = 0; k < 4; k++) {
                        float gw = xv[k + 2] - xv[k];
                        float pw = xv[k] + xv[k + 1] + xv[k + 2];
                        float sw = pw + xv[k + 1];
                        A1[2][k] += smh * gw;
                        A2[2][k] += sw;
                        A3[2][k] += grh * pw;
                    }
                    if (kh == 0) {
#pragma unroll
                        for (int j = 0; j < 6; j++) C6[j] = xv[j];
                    } else {
#pragma unroll
                        for (int k = 0; k < 4; k++) CH[k] += xv[k + 1];
                    }
                }
            }
        }
        if (i >= 2) {
            int d = s - 1;
            int idx = (d * HHH + h) * WWW + w;
            float vs[4], vl[4];
#pragma unroll
            for (int k = 0; k < 4; k++) {
                float gx = A1[0][k] + A1[1][k] + A1[2][k];
                float gy = A2[2][k] - A2[0][k];
                float gz = A3[0][k] + 2.f * A3[1][k] + A3[2][k];
                vs[k] = sqrtf(gx * gx + gy * gy + gz * gz);
                vl[k] = 6.f * P6[k + 1] - (P6[k] + P6[k + 2] + PH[k] + PP4[k] + C6[k + 1]);
            }
            st_h4(osob, idx, vs[0], vs[1], vs[2], vs[3]);
            st_h4(olap, idx, vl[0], vl[1], vl[2], vl[3]);
        }
#pragma unroll
        for (int k = 0; k < 4; k++) PP4[k] = P6[k + 1];
#pragma unroll
        for (int j = 0; j < 6; j++) P6[j] = C6[j];
#pragma unroll
        for (int k = 0; k < 4; k++) PH[k] = CH[k];
    }
}

// ---- Laplacian body (fallback path only) -----------------------------------
__device__ __forceinline__ void lap_body(int t, const float* __restrict__ a,
                                         const float* __restrict__ b,
                                         __half* __restrict__ oa, __half* __restrict__ ob) {
    int w = (t % W4) * 4;
    int h = (t / W4) % HHH;
    int d = t / (W4 * HHH);
    int idx = (d * HHH + h) * WWW + w;
    bool dok0 = d > 0, dok1 = d < DD - 1, hok0 = h > 0, hok1 = h < HHH - 1;
#pragma unroll
    for (int s = 0; s < 2; s++) {
        const float* p = s ? b : a;
        __half* o = s ? ob : oa;
        float4 c = *(const float4*)(p + idx);
        float m1 = (w > 0) ? p[idx - 1] : 0.f;
        float p4 = (w + 4 < WWW) ? p[idx + 4] : 0.f;
        float4 dm = ldg4(p, idx - HW, dok0);
        float4 dp = ldg4(p, idx + HW, dok1);
        float4 hm = ldg4(p, idx - WWW, hok0);
        float4 hp = ldg4(p, idx + WWW, hok1);
        st_h4(o, idx,
              6.f * c.x - (m1 + c.y + dm.x + dp.x + hm.x + hp.x),
              6.f * c.y - (c.x + c.z + dm.y + dp.y + hm.y + hp.y),
              6.f * c.z - (c.y + c.w + dm.z + dp.z + hm.z + hp.z),
              6.f * c.w - (c.z + p4 + dm.w + dp.w + hm.w + hp.w));
    }
}

// ---- Sobel body (fallback path only) ----------------------------------------
__device__ __forceinline__ void sobel_slice(const float* __restrict__ p, int s, int h, int w,
                                            float a1[4], float a2[4], float a3[4]) {
#pragma unroll
    for (int k = 0; k < 4; k++) { a1[k] = 0.f; a2[k] = 0.f; a3[k] = 0.f; }
#pragma unroll
    for (int kh = -1; kh <= 1; kh++) {
        int h2 = h + kh;
        if ((unsigned)h2 < (unsigned)HHH) {
            int rb = (s * HHH + h2) * WWW + w;
            float4 cen = *(const float4*)(p + rb);
            float xm = (w > 0) ? p[rb - 1] : 0.f;
            float xp = (w + 4 < WWW) ? p[rb + 4] : 0.f;
            float xv[6] = {xm, cen.x, cen.y, cen.z, cen.w, xp};
            float smh = (kh == 0) ? 2.f : 1.f;
            float grh = (float)kh;
#pragma unroll
            for (int k = 0; k < 4; k++) {
                float gw = xv[k + 2] - xv[k];
                float pw = xv[k] + xv[k + 1] + xv[k + 2];
                float sw = pw + xv[k + 1];
                a1[k] += smh * gw;
                a2[k] += sw;
                a3[k] += grh * pw;
            }
        }
    }
}

__device__ __forceinline__ void sobel_body(int t, const float* __restrict__ a,
                                           const float* __restrict__ b,
                                           __half* __restrict__ oa, __half* __restrict__ ob) {
    int w = (t % W4) * 4;
    int h = (t / W4) % HHH;
    int c = t / (W4 * HHH);
    int d0 = c * SC;

    float A1[2][3][4], A2[2][3][4], A3[2][3][4];
#pragma unroll
    for (int r = 0; r < 2; r++)
#pragma unroll
        for (int j = 0; j < 3; j++)
#pragma unroll
            for (int k = 0; k < 4; k++) { A1[r][j][k] = 0.f; A2[r][j][k] = 0.f; A3[r][j][k] = 0.f; }

#pragma unroll
    for (int i = 0; i < SC + 2; i++) {
        int s = d0 - 1 + i;
#pragma unroll
        for (int r = 0; r < 2; r++)
#pragma unroll
            for (int k = 0; k < 4; k++) {
                A1[r][0][k] = A1[r][1][k]; A2[r][0][k] = A2[r][1][k]; A3[r][0][k] = A3[r][1][k];
                A1[r][1][k] = A1[r][2][k]; A2[r][1][k] = A2[r][2][k]; A3[r][1][k] = A3[r][2][k];
            }
        if (s >= 0 && s < DD) {
            sobel_slice(a, s, h, w, A1[0][2], A2[0][2], A3[0][2]);
            sobel_slice(b, s, h, w, A1[1][2], A2[1][2], A3[1][2]);
        } else {
#pragma unroll
            for (int r = 0; r < 2; r++)
#pragma unroll
                for (int k = 0; k < 4; k++) { A1[r][2][k] = 0.f; A2[r][2][k] = 0.f; A3[r][2][k] = 0.f; }
        }
        if (i >= 2) {
            int d = s - 1;
            int idx = (d * HHH + h) * WWW + w;
            float va[4], vb[4];
#pragma unroll
            for (int k = 0; k < 4; k++) {
                float gx = A1[0][0][k] + A1[0][1][k] + A1[0][2][k];
                float gy = A2[0][2][k] - A2[0][0][k];
                float gz = A3[0][0][k] + 2.f * A3[0][1][k] + A3[0][2][k];
                va[k] = sqrtf(gx * gx + gy * gy + gz * gz);
                gx = A1[1][0][k] + A1[1][1][k] + A1[1][2][k];
                gy = A2[1][2][k] - A2[1][0][k];
                gz = A3[1][0][k] + 2.f * A3[1][1][k] + A3[1][2][k];
                vb[k] = sqrtf(gx * gx + gy * gy + gz * gz);
            }
            st_h4(oa, idx, va[0], va[1], va[2], va[3]);
            st_h4(ob, idx, vb[0], vb[1], vb[2], vb[3]);
        }
    }
}

// ---- W+H box sums of 5 moments ----------------------------------------------
__device__ __forceinline__ void q5_from(const float x[12], const float y[12], float q[5][4]) {
    float s0 = 0, s1 = 0, s2 = 0, s3 = 0, s4 = 0;
#pragma unroll
    for (int j = 0; j < 9; j++) {
        s0 += x[j]; s1 += y[j];
        s2 += x[j] * x[j]; s3 += y[j] * y[j]; s4 += x[j] * y[j];
    }
    q[0][0] = s0; q[1][0] = s1; q[2][0] = s2; q[3][0] = s3; q[4][0] = s4;
#pragma unroll
    for (int k = 1; k < 4; k++) {
        q[0][k] = q[0][k - 1] + x[k + 8] - x[k - 1];
        q[1][k] = q[1][k - 1] + y[k + 8] - y[k - 1];
        q[2][k] = q[2][k - 1] + x[k + 8] * x[k + 8] - x[k - 1] * x[k - 1];
        q[3][k] = q[3][k - 1] + y[k + 8] * y[k + 8] - y[k - 1] * y[k - 1];
        q[4][k] = q[4][k - 1] + x[k + 8] * y[k + 8] - x[k - 1] * y[k - 1];
    }
}

__device__ __forceinline__ void ld12(const float* __restrict__ p, int rowbase, int w, float x[12]) {
    bool lo = (w >= 4);
    bool hi = (w + 7 < WWW);
    float4 x0 = ldg4(p, rowbase + w - 4, lo);
    float4 x1 = *(const float4*)(p + rowbase + w);
    float4 x2 = ldg4(p, rowbase + w + 4, hi);
    x[0] = x0.x; x[1] = x0.y; x[2] = x0.z; x[3] = x0.w;
    x[4] = x1.x; x[5] = x1.y; x[6] = x1.z; x[7] = x1.w;
    x[8] = x2.x; x[9] = x2.y; x[10] = x2.z; x[11] = x2.w;
}

__device__ __forceinline__ void ld12(const __half* __restrict__ p, int rowbase, int w, float x[12]) {
    bool lo = (w >= 4);
    bool hi = (w + 7 < WWW);
    union { __half2 h2[2]; uint2 u; } u0, u1, u2;
    uint2 z = make_uint2(0, 0);
    u0.u = lo ? *(const uint2*)(p + rowbase + w - 4) : z;
    u1.u = *(const uint2*)(p + rowbase + w);
    u2.u = hi ? *(const uint2*)(p + rowbase + w + 4) : z;
    x[0] = __low2float(u0.h2[0]); x[1] = __high2float(u0.h2[0]);
    x[2] = __low2float(u0.h2[1]); x[3] = __high2float(u0.h2[1]);
    x[4] = __low2float(u1.h2[0]); x[5] = __high2float(u1.h2[0]);
    x[6] = __low2float(u1.h2[1]); x[7] = __high2float(u1.h2[1]);
    x[8] = __low2float(u2.h2[0]); x[9] = __high2float(u2.h2[0]);
    x[10] = __low2float(u2.h2[1]); x[11] = __high2float(u2.h2[1]);
}

template <typename T>
__device__ __forceinline__ void rowq5(const T* __restrict__ a, const T* __restrict__ b,
                                      int rowbase, int w, float q[5][4]) {
    float x[12], y[12];
    ld12(a, rowbase, w, x);
    ld12(b, rowbase, w, y);
    q5_from(x, y, q);
}

// Output: interleaved tile t (one pointer, [g][5][4] fp16).
template <typename T>
__device__ void whsum_body(int t_, const T* __restrict__ a, const T* __restrict__ b,
                           __half* __restrict__ t) {
    int w4 = t_ % W4;
    int w = w4 * 4;
    int d = (t_ / W4) % DD;
    int c = t_ / (W4 * DD);
    int h0 = c * HC;

    float S[5][4] = {{0}};
    for (int j = 0; j < 9; j++) {
        int r = h0 - 4 + j;
        if ((unsigned)r < (unsigned)HHH) {
            float q[5][4];
            rowq5(a, b, (d * HHH + r) * WWW, w, q);
#pragma unroll
            for (int qq = 0; qq < 5; qq++)
#pragma unroll
                for (int k = 0; k < 4; k++) S[qq][k] += q[qq][k];
        }
    }
    st_t5(t, (d * HHH + h0) * W4 + w4, S);
    for (int h = h0 + 1; h < h0 + HC; h++) {
        int rin = h + 4, rout = h - 5;
        if (rin < HHH) {
            float q[5][4];
            rowq5(a, b, (d * HHH + rin) * WWW, w, q);
#pragma unroll
            for (int qq = 0; qq < 5; qq++)
#pragma unroll
                for (int k = 0; k < 4; k++) S[qq][k] += q[qq][k];
        }
        if (rout >= 0) {
            float q[5][4];
            rowq5(a, b, (d * HHH + rout) * WWW, w, q);
#pragma unroll
            for (int qq = 0; qq < 5; qq++)
#pragma unroll
                for (int k = 0; k < 4; k++) S[qq][k] -= q[qq][k];
        }
        st_t5(t, (d * HHH + h) * W4 + w4, S);
    }
}

// ---- D box-sum + cc + reduction ---------------------------------------------
__device__ __forceinline__ float cc1(float s0, float s1, float s2, float s3, float s4) {
    const float wsz = 729.0f;
    const float inv = 1.0f / 729.0f;
    float uI = s0 * inv;
    float uJ = s1 * inv;
    float cross = s4 - uJ * s0 - uI * s1 + uI * uJ * wsz;
    float Iv = s2 - 2.0f * uI * s0 + uI * uI * wsz;
    float Jv = s3 - 2.0f * uJ * s1 + uJ * uJ * wsz;
    return cross * cross / (Iv * Jv + 1e-5f);
}

__device__ void dcc_body(int t_, const __half* __restrict__ tile,
                         double* __restrict__ acc, int pair) {
    int w4 = t_ % W4;
    int h = (t_ / W4) % HHH;
    int c = t_ / (W4 * HHH);
    int d0 = c * DC;

    float S[5][4] = {{0}};
    for (int j = 0; j < 9; j++) {
        int r = d0 - 4 + j;
        if ((unsigned)r < (unsigned)DD) {
            float v[5][4];
            ld_t5(tile, (r * HHH + h) * W4 + w4, v);
#pragma unroll
            for (int q = 0; q < 5; q++)
#pragma unroll
                for (int k = 0; k < 4; k++) S[q][k] += v[q][k];
        }
    }
    float local = 0.f;
#pragma unroll
    for (int k = 0; k < 4; k++) local += cc1(S[0][k], S[1][k], S[2][k], S[3][k], S[4][k]);
#pragma unroll
    for (int d = 1; d < DC; d++) {
        int rin = d0 + d + 4, rout = d0 + d - 5;
        if (rin < DD) {
            float v[5][4];
            ld_t5(tile, (rin * HHH + h) * W4 + w4, v);
#pragma unroll
            for (int q = 0; q < 5; q++)
#pragma unroll
                for (int k = 0; k < 4; k++) S[q][k] += v[q][k];
        }
        if (rout >= 0) {
            float v[5][4];
            ld_t5(tile, (rout * HHH + h) * W4 + w4, v);
#pragma unroll
            for (int q = 0; q < 5; q++)
#pragma unroll
                for (int k = 0; k < 4; k++) S[q][k] -= v[q][k];
        }
#pragma unroll
        for (int k = 0; k < 4; k++) local += cc1(S[0][k], S[1][k], S[2][k], S[3][k], S[4][k]);
    }

    for (int off = 32; off > 0; off >>= 1) local += __shfl_down(local, off);
    __shared__ float wsum_[4];
    if ((threadIdx.x & 63) == 0) wsum_[threadIdx.x >> 6] = local;
    __syncthreads();
    if (threadIdx.x == 0) {
        float s = wsum_[0] + wsum_[1] + wsum_[2] + wsum_[3];
        atomicAdd(&acc[pair], (double)s);
    }
}

// ---- Stage kernels (wide schedule) ------------------------------------------
// S1: fused sobel+lap (both volumes) + whsum_p0 (independent of fusion) + zero.
__global__ void __launch_bounds__(256, 4)
stage1w(const float* __restrict__ yt, const float* __restrict__ yp,
        __half* __restrict__ e1a, __half* __restrict__ e1b,
        __half* __restrict__ e2a, __half* __restrict__ e2b,
        __half* __restrict__ tA, double* __restrict__ acc) {
    int b = blockIdx.x;
    if (b < NB_FU) {
        int lb = xcd_swz(b, NB_FU);
        fused_body(lb * 256 + threadIdx.x, yt, e1a, e2a);
    } else if (b < 2 * NB_FU) {
        int lb = xcd_swz(b - NB_FU, NB_FU);
        fused_body(lb * 256 + threadIdx.x, yp, e1b, e2b);
    } else if (b < 2 * NB_FU + NB_WH) {
        int lb = xcd_swz(b - 2 * NB_FU, NB_WH);
        whsum_body<float>(lb * 256 + threadIdx.x, yt, yp, tA);
    } else {
        if (threadIdx.x < 3) acc[threadIdx.x] = 0.0;
    }
}

// S2: wh1(e1->tB) + wh2(e2->tC) + dcc0(tA->acc0)
__global__ void stage2m(const __half* __restrict__ e1a, const __half* __restrict__ e1b,
                        const __half* __restrict__ e2a, const __half* __restrict__ e2b,
                        __half* __restrict__ tB, __half* __restrict__ tC,
                        const __half* __restrict__ tA, double* __restrict__ acc) {
    int b = blockIdx.x;
    if (b < NB_WH) {
        int lb = xcd_swz(b, NB_WH);
        whsum_body<__half>(lb * 256 + threadIdx.x, e1a, e1b, tB);
    } else if (b < 2 * NB_WH) {
        int lb = xcd_swz(b - NB_WH, NB_WH);
        whsum_body<__half>(lb * 256 + threadIdx.x, e2a, e2b, tC);
    } else {
        int lb = xcd_swz(b - 2 * NB_WH, NB_DCC);
        dcc_body(lb * 256 + threadIdx.x, tA, acc, 0);
    }
}

// S3: dcc1(tB->acc1) + dcc2(tC->acc2)
__global__ void stage3m(const __half* __restrict__ tB, const __half* __restrict__ tC,
                        double* __restrict__ acc) {
    int b = blockIdx.x;
    if (b < NB_DCC) {
        int lb = xcd_swz(b, NB_DCC);
        dcc_body(lb * 256 + threadIdx.x, tB, acc, 1);
    } else {
        int lb = xcd_swz(b - NB_DCC, NB_DCC);
        dcc_body(lb * 256 + threadIdx.x, tC, acc, 2);
    }
}

// ---- Stage kernels (fallback schedule) --------------------------------------
__global__ void stage1(const float* __restrict__ yt, const float* __restrict__ yp,
                       __half* __restrict__ e1a, __half* __restrict__ e1b,
                       __half* __restrict__ e2a, __half* __restrict__ e2b,
                       __half* __restrict__ tA, double* __restrict__ acc) {
    int b = blockIdx.x;
    if (b < NB_WH) {
        int lb = xcd_swz(b, NB_WH);
        whsum_body<float>(lb * 256 + threadIdx.x, yt, yp, tA);
    } else if (b < NB_WH + NB_SO) {
        int lb = xcd_swz(b - NB_WH, NB_SO);
        sobel_body(lb * 256 + threadIdx.x, yt, yp, e2a, e2b);
    } else if (b < NB_WH + NB_SO + NB_LAP) {
        int lb = xcd_swz(b - NB_WH - NB_SO, NB_LAP);
        lap_body(lb * 256 + threadIdx.x, yt, yp, e1a, e1b);
    } else {
        if (threadIdx.x < 3) acc[threadIdx.x] = 0.0;
    }
}

__global__ void stage23(const __half* __restrict__ ea, const __half* __restrict__ eb,
                        __half* __restrict__ o, const __half* __restrict__ i,
                        double* __restrict__ acc, int pair) {
    int b = blockIdx.x;
    if (b < NB_WH) {
        int lb = xcd_swz(b, NB_WH);
        whsum_body<__half>(lb * 256 + threadIdx.x, ea, eb, o);
    } else {
        int lb = xcd_swz(b - NB_WH, NB_DCC);
        dcc_body(lb * 256 + threadIdx.x, i, acc, pair);
    }
}

__global__ void dcc_k(const __half* __restrict__ tile, double* __restrict__ acc, int pair) {
    int lb = xcd_swz(blockIdx.x, NB_DCC);
    dcc_body(lb * 256 + threadIdx.x, tile, acc, pair);
}

__global__ void finalize_k(const double* __restrict__ acc, float* __restrict__ out) {
    if (threadIdx.x == 0) {
        double v = 0.8 * acc[0] + 0.1 * acc[1] + 0.1 * acc[2];
        out[0] = (float)(-v / (double)NV);
    }
}

extern "C" void kernel_launch(void* const* d_in, const int* in_sizes, int n_in,
                              void* d_out, int out_size, void* d_ws, size_t ws_size,
                              hipStream_t stream) {
    const float* yt = (const float*)d_in[0];
    const float* yp = (const float*)d_in[1];
    float* out = (float*)d_out;

    // ws layout: acc(256B) | e1a e1b e2a e2b | tA(5nv) | tB(5nv) [| tC(5nv)]
    double* acc = (double*)d_ws;
    __half* base = (__half*)((char*)d_ws + 256);
    size_t nv = (size_t)NV;
    __half* e1a = base + 0 * nv;
    __half* e1b = base + 1 * nv;
    __half* e2a = base + 2 * nv;
    __half* e2b = base + 3 * nv;
    __half* tA = base + 4 * nv;   // interleaved 5-moment tile (5*nv halves)
    __half* tB = base + 9 * nv;
    __half* tC = base + 14 * nv;  // wide schedule only

    bool wide = ws_size >= 256 + 19 * nv * sizeof(__half);

    dim3 blk(256);

    if (wide) {
        // S1: fused sobel+lap + whsum_p0 + zero
        hipLaunchKernelGGL(stage1w, dim3(2 * NB_FU + NB_WH + 1), blk, 0, stream,
                           yt, yp, e1a, e1b, e2a, e2b, tA, acc);
        // S2: wh1 + wh2 + dcc0
        hipLaunchKernelGGL(stage2m, dim3(2 * NB_WH + NB_DCC), blk, 0, stream,
                           e1a, e1b, e2a, e2b, tB, tC, tA, acc);
        // S3: dcc1 + dcc2
        hipLaunchKernelGGL(stage3m, dim3(2 * NB_DCC), blk, 0, stream, tB, tC, acc);
    } else {
        // Fallback (2 tile sets)
        hipLaunchKernelGGL(stage1, dim3(NB_WH + NB_SO + NB_LAP + 1), blk, 0, stream,
                           yt, yp, e1a, e1b, e2a, e2b, tA, acc);
        hipLaunchKernelGGL(stage23, dim3(NB_WH + NB_DCC), blk, 0, stream,
                           e1a, e1b, tB, tA, acc, 0);
        hipLaunchKernelGGL(stage23, dim3(NB_WH + NB_DCC), blk, 0, stream,
                           e2a, e2b, tA, tB, acc, 1);
        hipLaunchKernelGGL(dcc_k, dim3(NB_DCC), blk, 0, stream, tA, acc, 2);
    }

    hipLaunchKernelGGL(finalize_k, dim3(1), dim3(1), 0, stream, acc, out);
}

// Round 9
// 328.129 us; speedup vs baseline: 1.7009x; 1.0231x over previous
//
#include <hip/hip_runtime.h>
#include <hip/hip_fp16.h>
#include <math.h>

// Volume dims (1,1,160,192,160) fp32
// Base = R5/R8 (session-best 333-336 us). R9: SCF 4->8 (fused warm-up
// amortization: 13.5 -> 11.25 loads/output, ring state unchanged -> no spill).
// 8-wide voxel variants (R1/R6/R7) all spill: hipcc pins these kernels at
// 64 VGPR and spills past ~64 live floats. 4-wide bodies are the widest
// spill-free config.
#define DD 160
#define HHH 192
#define WWW 160
constexpr int HW = HHH * WWW;          // 30720
constexpr int NV = DD * HHH * WWW;     // 4915200
constexpr int W4 = WWW / 4;            // 40
constexpr int HC = 4;                  // whsum H-chunk (measured best)
constexpr int DC = 4;                  // dcc D-chunk (measured best; 8 regressed)
constexpr int SC = 8;                  // sobel D-chunk (fallback path only)
constexpr int SCF = 8;                 // fused sobel+lap D-chunk (was 4)

constexpr int NB_WH  = (W4 * DD * (HHH / HC)) / 256;   // 1200
constexpr int NB_SO  = (W4 * HHH * (DD / SC)) / 256;   // 600  (fallback)
constexpr int NB_LAP = (NV / 4) / 256;                 // 4800 (fallback)
constexpr int NB_DCC = (W4 * HHH * (DD / DC)) / 256;   // 1200
constexpr int NB_FU  = (W4 * HHH * (DD / SCF)) / 256;  // 600 (per volume)

// Per-phase XCD-chunked swizzle (proven: halves FETCH via L2 locality).
// Valid bijection when n % 8 == 0 (all phase ranges here are).
__device__ __forceinline__ int xcd_swz(int b, int n) {
    int q = n >> 3;
    return (b & 7) * q + (b >> 3);
}

__device__ __forceinline__ float4 ldg4(const float* __restrict__ p, int idx, bool ok) {
    float4 z = make_float4(0.f, 0.f, 0.f, 0.f);
    return ok ? *(const float4*)(p + idx) : z;
}

__device__ __forceinline__ void st_h4(__half* __restrict__ t, int idx,
                                      float s0, float s1, float s2, float s3) {
    union { __half2 h2[2]; uint2 u; } pk;
    pk.h2[0] = __floats2half2_rn(s0, s1);
    pk.h2[1] = __floats2half2_rn(s2, s3);
    *(uint2*)(t + idx) = pk.u;  // idx%4==0 -> 8B aligned
}

// ---- Interleaved 5-moment tile: group g holds [5][4] fp16 = 40B contiguous.
// A wave's 64 lanes write 2560B contiguous -> full 128B lines, no RMW.
__device__ __forceinline__ void st_t5(__half* __restrict__ t, int g, const float S[5][4]) {
    __half* p = t + (size_t)g * 20;
#pragma unroll
    for (int q = 0; q < 5; q++) {
        union { __half2 h2[2]; uint2 u; } pk;
        pk.h2[0] = __floats2half2_rn(S[q][0], S[q][1]);
        pk.h2[1] = __floats2half2_rn(S[q][2], S[q][3]);
        *(uint2*)(p + q * 4) = pk.u;  // 40B-aligned base, +8B steps
    }
}

__device__ __forceinline__ void ld_t5(const __half* __restrict__ t, int g, float v[5][4]) {
    const __half* p = t + (size_t)g * 20;
#pragma unroll
    for (int q = 0; q < 5; q++) {
        union { __half2 h2[2]; uint2 u; } pk;
        pk.u = *(const uint2*)(p + q * 4);
        v[q][0] = __low2float(pk.h2[0]); v[q][1] = __high2float(pk.h2[0]);
        v[q][2] = __low2float(pk.h2[1]); v[q][3] = __high2float(pk.h2[1]);
    }
}

// ---- Fused sobel+lap body, ONE volume per thread ---------------------------
__device__ void fused_body(int t, const float* __restrict__ p,
                           __half* __restrict__ olap, __half* __restrict__ osob) {
    int w = (t % W4) * 4;
    int h = (t / W4) % HHH;
    int c = t / (W4 * HHH);
    int d0 = c * SCF;

    float A1[3][4], A2[3][4], A3[3][4];
    float P6[6], PP4[4], PH[4];
#pragma unroll
    for (int j = 0; j < 3; j++)
#pragma unroll
        for (int k = 0; k < 4; k++) { A1[j][k] = 0.f; A2[j][k] = 0.f; A3[j][k] = 0.f; }
#pragma unroll
    for (int k = 0; k < 6; k++) P6[k] = 0.f;
#pragma unroll
    for (int k = 0; k < 4; k++) { PP4[k] = 0.f; PH[k] = 0.f; }

#pragma unroll
    for (int i = 0; i < SCF + 2; i++) {
        int s = d0 - 1 + i;
#pragma unroll
        for (int k = 0; k < 4; k++) {
            A1[0][k] = A1[1][k]; A2[0][k] = A2[1][k]; A3[0][k] = A3[1][k];
            A1[1][k] = A1[2][k]; A2[1][k] = A2[2][k]; A3[1][k] = A3[2][k];
        }
        float C6[6] = {0.f, 0.f, 0.f, 0.f, 0.f, 0.f};
        float CH[4] = {0.f, 0.f, 0.f, 0.f};
#pragma unroll
        for (int k = 0; k < 4; k++) { A1[2][k] = 0.f; A2[2][k] = 0.f; A3[2][k] = 0.f; }
        if (s >= 0 && s < DD) {
#pragma unroll
            for (int kh = -1; kh <= 1; kh++) {
                int h2 = h + kh;
                if ((unsigned)h2 < (unsigned)HHH) {
                    int rb = (s * HHH + h2) * WWW + w;
                    float4 cen = *(const float4*)(p + rb);
                    float xm = (w > 0) ? p[rb - 1] : 0.f;
                    float xp = (w + 4 < WWW) ? p[rb + 4] : 0.f;
                    float xv[6] = {xm, cen.x, cen.y, cen.z, cen.w, xp};
                    float smh = (kh == 0) ? 2.f : 1.f;
                    float grh = (float)kh;
#pragma unroll
                    for (int k = 0; k < 4; k++) {
                        float gw = xv[k + 2] - xv[k];
                        float pw = xv[k] + xv[k + 1] + xv[k + 2];
                        float sw = pw + xv[k + 1];
                        A1[2][k] += smh * gw;
                        A2[2][k] += sw;
                        A3[2][k] += grh * pw;
                    }
                    if (kh == 0) {
#pragma unroll
                        for (int j = 0; j < 6; j++) C6[j] = xv[j];
                    } else {
#pragma unroll
                        for (int k = 0; k < 4; k++) CH[k] += xv[k + 1];
                    }
                }
            }
        }
        if (i >= 2) {
            int d = s - 1;
            int idx = (d * HHH + h) * WWW + w;
            float vs[4], vl[4];
#pragma unroll
            for (int k = 0; k < 4; k++) {
                float gx = A1[0][k] + A1[1][k] + A1[2][k];
                float gy = A2[2][k] - A2[0][k];
                float gz = A3[0][k] + 2.f * A3[1][k] + A3[2][k];
                vs[k] = sqrtf(gx * gx + gy * gy + gz * gz);
                vl[k] = 6.f * P6[k + 1] - (P6[k] + P6[k + 2] + PH[k] + PP4[k] + C6[k + 1]);
            }
            st_h4(osob, idx, vs[0], vs[1], vs[2], vs[3]);
            st_h4(olap, idx, vl[0], vl[1], vl[2], vl[3]);
        }
#pragma unroll
        for (int k = 0; k < 4; k++) PP4[k] = P6[k + 1];
#pragma unroll
        for (int j = 0; j < 6; j++) P6[j] = C6[j];
#pragma unroll
        for (int k = 0; k < 4; k++) PH[k] = CH[k];
    }
}

// ---- Laplacian body (fallback path only) -----------------------------------
__device__ __forceinline__ void lap_body(int t, const float* __restrict__ a,
                                         const float* __restrict__ b,
                                         __half* __restrict__ oa, __half* __restrict__ ob) {
    int w = (t % W4) * 4;
    int h = (t / W4) % HHH;
    int d = t / (W4 * HHH);
    int idx = (d * HHH + h) * WWW + w;
    bool dok0 = d > 0, dok1 = d < DD - 1, hok0 = h > 0, hok1 = h < HHH - 1;
#pragma unroll
    for (int s = 0; s < 2; s++) {
        const float* p = s ? b : a;
        __half* o = s ? ob : oa;
        float4 c = *(const float4*)(p + idx);
        float m1 = (w > 0) ? p[idx - 1] : 0.f;
        float p4 = (w + 4 < WWW) ? p[idx + 4] : 0.f;
        float4 dm = ldg4(p, idx - HW, dok0);
        float4 dp = ldg4(p, idx + HW, dok1);
        float4 hm = ldg4(p, idx - WWW, hok0);
        float4 hp = ldg4(p, idx + WWW, hok1);
        st_h4(o, idx,
              6.f * c.x - (m1 + c.y + dm.x + dp.x + hm.x + hp.x),
              6.f * c.y - (c.x + c.z + dm.y + dp.y + hm.y + hp.y),
              6.f * c.z - (c.y + c.w + dm.z + dp.z + hm.z + hp.z),
              6.f * c.w - (c.z + p4 + dm.w + dp.w + hm.w + hp.w));
    }
}

// ---- Sobel body (fallback path only) ----------------------------------------
__device__ __forceinline__ void sobel_slice(const float* __restrict__ p, int s, int h, int w,
                                            float a1[4], float a2[4], float a3[4]) {
#pragma unroll
    for (int k = 0; k < 4; k++) { a1[k] = 0.f; a2[k] = 0.f; a3[k] = 0.f; }
#pragma unroll
    for (int kh = -1; kh <= 1; kh++) {
        int h2 = h + kh;
        if ((unsigned)h2 < (unsigned)HHH) {
            int rb = (s * HHH + h2) * WWW + w;
            float4 cen = *(const float4*)(p + rb);
            float xm = (w > 0) ? p[rb - 1] : 0.f;
            float xp = (w + 4 < WWW) ? p[rb + 4] : 0.f;
            float xv[6] = {xm, cen.x, cen.y, cen.z, cen.w, xp};
            float smh = (kh == 0) ? 2.f : 1.f;
            float grh = (float)kh;
#pragma unroll
            for (int k = 0; k < 4; k++) {
                float gw = xv[k + 2] - xv[k];
                float pw = xv[k] + xv[k + 1] + xv[k + 2];
                float sw = pw + xv[k + 1];
                a1[k] += smh * gw;
                a2[k] += sw;
                a3[k] += grh * pw;
            }
        }
    }
}

__device__ __forceinline__ void sobel_body(int t, const float* __restrict__ a,
                                           const float* __restrict__ b,
                                           __half* __restrict__ oa, __half* __restrict__ ob) {
    int w = (t % W4) * 4;
    int h = (t / W4) % HHH;
    int c = t / (W4 * HHH);
    int d0 = c * SC;

    float A1[2][3][4], A2[2][3][4], A3[2][3][4];
#pragma unroll
    for (int r = 0; r < 2; r++)
#pragma unroll
        for (int j = 0; j < 3; j++)
#pragma unroll
            for (int k = 0; k < 4; k++) { A1[r][j][k] = 0.f; A2[r][j][k] = 0.f; A3[r][j][k] = 0.f; }

#pragma unroll
    for (int i = 0; i < SC + 2; i++) {
        int s = d0 - 1 + i;
#pragma unroll
        for (int r = 0; r < 2; r++)
#pragma unroll
            for (int k = 0; k < 4; k++) {
                A1[r][0][k] = A1[r][1][k]; A2[r][0][k] = A2[r][1][k]; A3[r][0][k] = A3[r][1][k];
                A1[r][1][k] = A1[r][2][k]; A2[r][1][k] = A2[r][2][k]; A3[r][1][k] = A3[r][2][k];
            }
        if (s >= 0 && s < DD) {
            sobel_slice(a, s, h, w, A1[0][2], A2[0][2], A3[0][2]);
            sobel_slice(b, s, h, w, A1[1][2], A2[1][2], A3[1][2]);
        } else {
#pragma unroll
            for (int r = 0; r < 2; r++)
#pragma unroll
                for (int k = 0; k < 4; k++) { A1[r][2][k] = 0.f; A2[r][2][k] = 0.f; A3[r][2][k] = 0.f; }
        }
        if (i >= 2) {
            int d = s - 1;
            int idx = (d * HHH + h) * WWW + w;
            float va[4], vb[4];
#pragma unroll
            for (int k = 0; k < 4; k++) {
                float gx = A1[0][0][k] + A1[0][1][k] + A1[0][2][k];
                float gy = A2[0][2][k] - A2[0][0][k];
                float gz = A3[0][0][k] + 2.f * A3[0][1][k] + A3[0][2][k];
                va[k] = sqrtf(gx * gx + gy * gy + gz * gz);
                gx = A1[1][0][k] + A1[1][1][k] + A1[1][2][k];
                gy = A2[1][2][k] - A2[1][0][k];
                gz = A3[1][0][k] + 2.f * A3[1][1][k] + A3[1][2][k];
                vb[k] = sqrtf(gx * gx + gy * gy + gz * gz);
            }
            st_h4(oa, idx, va[0], va[1], va[2], va[3]);
            st_h4(ob, idx, vb[0], vb[1], vb[2], vb[3]);
        }
    }
}

// ---- W+H box sums of 5 moments ----------------------------------------------
__device__ __forceinline__ void q5_from(const float x[12], const float y[12], float q[5][4]) {
    float s0 = 0, s1 = 0, s2 = 0, s3 = 0, s4 = 0;
#pragma unroll
    for (int j = 0; j < 9; j++) {
        s0 += x[j]; s1 += y[j];
        s2 += x[j] * x[j]; s3 += y[j] * y[j]; s4 += x[j] * y[j];
    }
    q[0][0] = s0; q[1][0] = s1; q[2][0] = s2; q[3][0] = s3; q[4][0] = s4;
#pragma unroll
    for (int k = 1; k < 4; k++) {
        q[0][k] = q[0][k - 1] + x[k + 8] - x[k - 1];
        q[1][k] = q[1][k - 1] + y[k + 8] - y[k - 1];
        q[2][k] = q[2][k - 1] + x[k + 8] * x[k + 8] - x[k - 1] * x[k - 1];
        q[3][k] = q[3][k - 1] + y[k + 8] * y[k + 8] - y[k - 1] * y[k - 1];
        q[4][k] = q[4][k - 1] + x[k + 8] * y[k + 8] - x[k - 1] * y[k - 1];
    }
}

__device__ __forceinline__ void ld12(const float* __restrict__ p, int rowbase, int w, float x[12]) {
    bool lo = (w >= 4);
    bool hi = (w + 7 < WWW);
    float4 x0 = ldg4(p, rowbase + w - 4, lo);
    float4 x1 = *(const float4*)(p + rowbase + w);
    float4 x2 = ldg4(p, rowbase + w + 4, hi);
    x[0] = x0.x; x[1] = x0.y; x[2] = x0.z; x[3] = x0.w;
    x[4] = x1.x; x[5] = x1.y; x[6] = x1.z; x[7] = x1.w;
    x[8] = x2.x; x[9] = x2.y; x[10] = x2.z; x[11] = x2.w;
}

__device__ __forceinline__ void ld12(const __half* __restrict__ p, int rowbase, int w, float x[12]) {
    bool lo = (w >= 4);
    bool hi = (w + 7 < WWW);
    union { __half2 h2[2]; uint2 u; } u0, u1, u2;
    uint2 z = make_uint2(0, 0);
    u0.u = lo ? *(const uint2*)(p + rowbase + w - 4) : z;
    u1.u = *(const uint2*)(p + rowbase + w);
    u2.u = hi ? *(const uint2*)(p + rowbase + w + 4) : z;
    x[0] = __low2float(u0.h2[0]); x[1] = __high2float(u0.h2[0]);
    x[2] = __low2float(u0.h2[1]); x[3] = __high2float(u0.h2[1]);
    x[4] = __low2float(u1.h2[0]); x[5] = __high2float(u1.h2[0]);
    x[6] = __low2float(u1.h2[1]); x[7] = __high2float(u1.h2[1]);
    x[8] = __low2float(u2.h2[0]); x[9] = __high2float(u2.h2[0]);
    x[10] = __low2float(u2.h2[1]); x[11] = __high2float(u2.h2[1]);
}

template <typename T>
__device__ __forceinline__ void rowq5(const T* __restrict__ a, const T* __restrict__ b,
                                      int rowbase, int w, float q[5][4]) {
    float x[12], y[12];
    ld12(a, rowbase, w, x);
    ld12(b, rowbase, w, y);
    q5_from(x, y, q);
}

// Output: interleaved tile t (one pointer, [g][5][4] fp16).
template <typename T>
__device__ void whsum_body(int t_, const T* __restrict__ a, const T* __restrict__ b,
                           __half* __restrict__ t) {
    int w4 = t_ % W4;
    int w = w4 * 4;
    int d = (t_ / W4) % DD;
    int c = t_ / (W4 * DD);
    int h0 = c * HC;

    float S[5][4] = {{0}};
    for (int j = 0; j < 9; j++) {
        int r = h0 - 4 + j;
        if ((unsigned)r < (unsigned)HHH) {
            float q[5][4];
            rowq5(a, b, (d * HHH + r) * WWW, w, q);
#pragma unroll
            for (int qq = 0; qq < 5; qq++)
#pragma unroll
                for (int k = 0; k < 4; k++) S[qq][k] += q[qq][k];
        }
    }
    st_t5(t, (d * HHH + h0) * W4 + w4, S);
    for (int h = h0 + 1; h < h0 + HC; h++) {
        int rin = h + 4, rout = h - 5;
        if (rin < HHH) {
            float q[5][4];
            rowq5(a, b, (d * HHH + rin) * WWW, w, q);
#pragma unroll
            for (int qq = 0; qq < 5; qq++)
#pragma unroll
                for (int k = 0; k < 4; k++) S[qq][k] += q[qq][k];
        }
        if (rout >= 0) {
            float q[5][4];
            rowq5(a, b, (d * HHH + rout) * WWW, w, q);
#pragma unroll
            for (int qq = 0; qq < 5; qq++)
#pragma unroll
                for (int k = 0; k < 4; k++) S[qq][k] -= q[qq][k];
        }
        st_t5(t, (d * HHH + h) * W4 + w4, S);
    }
}

// ---- D box-sum + cc + reduction ---------------------------------------------
__device__ __forceinline__ float cc1(float s0, float s1, float s2, float s3, float s4) {
    const float wsz = 729.0f;
    const float inv = 1.0f / 729.0f;
    float uI = s0 * inv;
    float uJ = s1 * inv;
    float cross = s4 - uJ * s0 - uI * s1 + uI * uJ * wsz;
    float Iv = s2 - 2.0f * uI * s0 + uI * uI * wsz;
    float Jv = s3 - 2.0f * uJ * s1 + uJ * uJ * wsz;
    return cross * cross / (Iv * Jv + 1e-5f);
}

__device__ void dcc_body(int t_, const __half* __restrict__ tile,
                         double* __restrict__ acc, int pair) {
    int w4 = t_ % W4;
    int h = (t_ / W4) % HHH;
    int c = t_ / (W4 * HHH);
    int d0 = c * DC;

    float S[5][4] = {{0}};
    for (int j = 0; j < 9; j++) {
        int r = d0 - 4 + j;
        if ((unsigned)r < (unsigned)DD) {
            float v[5][4];
            ld_t5(tile, (r * HHH + h) * W4 + w4, v);
#pragma unroll
            for (int q = 0; q < 5; q++)
#pragma unroll
                for (int k = 0; k < 4; k++) S[q][k] += v[q][k];
        }
    }
    float local = 0.f;
#pragma unroll
    for (int k = 0; k < 4; k++) local += cc1(S[0][k], S[1][k], S[2][k], S[3][k], S[4][k]);
#pragma unroll
    for (int d = 1; d < DC; d++) {
        int rin = d0 + d + 4, rout = d0 + d - 5;
        if (rin < DD) {
            float v[5][4];
            ld_t5(tile, (rin * HHH + h) * W4 + w4, v);
#pragma unroll
            for (int q = 0; q < 5; q++)
#pragma unroll
                for (int k = 0; k < 4; k++) S[q][k] += v[q][k];
        }
        if (rout >= 0) {
            float v[5][4];
            ld_t5(tile, (rout * HHH + h) * W4 + w4, v);
#pragma unroll
            for (int q = 0; q < 5; q++)
#pragma unroll
                for (int k = 0; k < 4; k++) S[q][k] -= v[q][k];
        }
#pragma unroll
        for (int k = 0; k < 4; k++) local += cc1(S[0][k], S[1][k], S[2][k], S[3][k], S[4][k]);
    }

    for (int off = 32; off > 0; off >>= 1) local += __shfl_down(local, off);
    __shared__ float wsum_[4];
    if ((threadIdx.x & 63) == 0) wsum_[threadIdx.x >> 6] = local;
    __syncthreads();
    if (threadIdx.x == 0) {
        float s = wsum_[0] + wsum_[1] + wsum_[2] + wsum_[3];
        atomicAdd(&acc[pair], (double)s);
    }
}

// ---- Stage kernels (wide schedule) ------------------------------------------
// S1: fused sobel+lap (both volumes) + whsum_p0 (independent of fusion) + zero.
__global__ void __launch_bounds__(256, 4)
stage1w(const float* __restrict__ yt, const float* __restrict__ yp,
        __half* __restrict__ e1a, __half* __restrict__ e1b,
        __half* __restrict__ e2a, __half* __restrict__ e2b,
        __half* __restrict__ tA, double* __restrict__ acc) {
    int b = blockIdx.x;
    if (b < NB_FU) {
        int lb = xcd_swz(b, NB_FU);
        fused_body(lb * 256 + threadIdx.x, yt, e1a, e2a);
    } else if (b < 2 * NB_FU) {
        int lb = xcd_swz(b - NB_FU, NB_FU);
        fused_body(lb * 256 + threadIdx.x, yp, e1b, e2b);
    } else if (b < 2 * NB_FU + NB_WH) {
        int lb = xcd_swz(b - 2 * NB_FU, NB_WH);
        whsum_body<float>(lb * 256 + threadIdx.x, yt, yp, tA);
    } else {
        if (threadIdx.x < 3) acc[threadIdx.x] = 0.0;
    }
}

// S2: wh1(e1->tB) + wh2(e2->tC) + dcc0(tA->acc0)
__global__ void stage2m(const __half* __restrict__ e1a, const __half* __restrict__ e1b,
                        const __half* __restrict__ e2a, const __half* __restrict__ e2b,
                        __half* __restrict__ tB, __half* __restrict__ tC,
                        const __half* __restrict__ tA, double* __restrict__ acc) {
    int b = blockIdx.x;
    if (b < NB_WH) {
        int lb = xcd_swz(b, NB_WH);
        whsum_body<__half>(lb * 256 + threadIdx.x, e1a, e1b, tB);
    } else if (b < 2 * NB_WH) {
        int lb = xcd_swz(b - NB_WH, NB_WH);
        whsum_body<__half>(lb * 256 + threadIdx.x, e2a, e2b, tC);
    } else {
        int lb = xcd_swz(b - 2 * NB_WH, NB_DCC);
        dcc_body(lb * 256 + threadIdx.x, tA, acc, 0);
    }
}

// S3: dcc1(tB->acc1) + dcc2(tC->acc2)
__global__ void stage3m(const __half* __restrict__ tB, const __half* __restrict__ tC,
                        double* __restrict__ acc) {
    int b = blockIdx.x;
    if (b < NB_DCC) {
        int lb = xcd_swz(b, NB_DCC);
        dcc_body(lb * 256 + threadIdx.x, tB, acc, 1);
    } else {
        int lb = xcd_swz(b - NB_DCC, NB_DCC);
        dcc_body(lb * 256 + threadIdx.x, tC, acc, 2);
    }
}

// ---- Stage kernels (fallback schedule) --------------------------------------
__global__ void stage1(const float* __restrict__ yt, const float* __restrict__ yp,
                       __half* __restrict__ e1a, __half* __restrict__ e1b,
                       __half* __restrict__ e2a, __half* __restrict__ e2b,
                       __half* __restrict__ tA, double* __restrict__ acc) {
    int b = blockIdx.x;
    if (b < NB_WH) {
        int lb = xcd_swz(b, NB_WH);
        whsum_body<float>(lb * 256 + threadIdx.x, yt, yp, tA);
    } else if (b < NB_WH + NB_SO) {
        int lb = xcd_swz(b - NB_WH, NB_SO);
        sobel_body(lb * 256 + threadIdx.x, yt, yp, e2a, e2b);
    } else if (b < NB_WH + NB_SO + NB_LAP) {
        int lb = xcd_swz(b - NB_WH - NB_SO, NB_LAP);
        lap_body(lb * 256 + threadIdx.x, yt, yp, e1a, e1b);
    } else {
        if (threadIdx.x < 3) acc[threadIdx.x] = 0.0;
    }
}

__global__ void stage23(const __half* __restrict__ ea, const __half* __restrict__ eb,
                        __half* __restrict__ o, const __half* __restrict__ i,
                        double* __restrict__ acc, int pair) {
    int b = blockIdx.x;
    if (b < NB_WH) {
        int lb = xcd_swz(b, NB_WH);
        whsum_body<__half>(lb * 256 + threadIdx.x, ea, eb, o);
    } else {
        int lb = xcd_swz(b - NB_WH, NB_DCC);
        dcc_body(lb * 256 + threadIdx.x, i, acc, pair);
    }
}

__global__ void dcc_k(const __half* __restrict__ tile, double* __restrict__ acc, int pair) {
    int lb = xcd_swz(blockIdx.x, NB_DCC);
    dcc_body(lb * 256 + threadIdx.x, tile, acc, pair);
}

__global__ void finalize_k(const double* __restrict__ acc, float* __restrict__ out) {
    if (threadIdx.x == 0) {
        double v = 0.8 * acc[0] + 0.1 * acc[1] + 0.1 * acc[2];
        out[0] = (float)(-v / (double)NV);
    }
}

extern "C" void kernel_launch(void* const* d_in, const int* in_sizes, int n_in,
                              void* d_out, int out_size, void* d_ws, size_t ws_size,
                              hipStream_t stream) {
    const float* yt = (const float*)d_in[0];
    const float* yp = (const float*)d_in[1];
    float* out = (float*)d_out;

    // ws layout: acc(256B) | e1a e1b e2a e2b | tA(5nv) | tB(5nv) [| tC(5nv)]
    double* acc = (double*)d_ws;
    __half* base = (__half*)((char*)d_ws + 256);
    size_t nv = (size_t)NV;
    __half* e1a = base + 0 * nv;
    __half* e1b = base + 1 * nv;
    __half* e2a = base + 2 * nv;
    __half* e2b = base + 3 * nv;
    __half* tA = base + 4 * nv;   // interleaved 5-moment tile (5*nv halves)
    __half* tB = base + 9 * nv;
    __half* tC = base + 14 * nv;  // wide schedule only

    bool wide = ws_size >= 256 + 19 * nv * sizeof(__half);

    dim3 blk(256);

    if (wide) {
        // S1: fused sobel+lap + whsum_p0 + zero
        hipLaunchKernelGGL(stage1w, dim3(2 * NB_FU + NB_WH + 1), blk, 0, stream,
                           yt, yp, e1a, e1b, e2a, e2b, tA, acc);
        // S2: wh1 + wh2 + dcc0
        hipLaunchKernelGGL(stage2m, dim3(2 * NB_WH + NB_DCC), blk, 0, stream,
                           e1a, e1b, e2a, e2b, tB, tC, tA, acc);
        // S3: dcc1 + dcc2
        hipLaunchKernelGGL(stage3m, dim3(2 * NB_DCC), blk, 0, stream, tB, tC, acc);
    } else {
        // Fallback (2 tile sets)
        hipLaunchKernelGGL(stage1, dim3(NB_WH + NB_SO + NB_LAP + 1), blk, 0, stream,
                           yt, yp, e1a, e1b, e2a, e2b, tA, acc);
        hipLaunchKernelGGL(stage23, dim3(NB_WH + NB_DCC), blk, 0, stream,
                           e1a, e1b, tB, tA, acc, 0);
        hipLaunchKernelGGL(stage23, dim3(NB_WH + NB_DCC), blk, 0, stream,
                           e2a, e2b, tA, tB, acc, 1);
        hipLaunchKernelGGL(dcc_k, dim3(NB_DCC), blk, 0, stream, tA, acc, 2);
    }

    hipLaunchKernelGGL(finalize_k, dim3(1), dim3(1), 0, stream, acc, out);
}